// Round 9
// baseline (724.909 us; speedup 1.0000x reference)
//
#include <hip/hip_runtime.h>
#include <hip/hip_fp16.h>

#define N_NODES 50000
#define N_EDGES 800000
#define IN_C 128
#define HID 32
#define HC 128
#define OUT_C 16
#define NGRAPH 64
#define PNB 125  // nodes per block in pool
#define TPB 8    // targets (waves) per block in edge attn: 512-thread blocks
                 // raise occupancy past the small-WG slot limit (was 2 -> 39% occ)

typedef __attribute__((ext_vector_type(8))) _Float16 half8;
typedef __attribute__((ext_vector_type(4))) _Float16 half4v;
typedef __attribute__((ext_vector_type(2))) _Float16 half2v;
typedef __attribute__((ext_vector_type(4))) float floatx4;

// ---------------- CSR build ----------------
__global__ void k_hist(const int* __restrict__ tgt, int* __restrict__ deg) {
  int i = blockIdx.x * blockDim.x + threadIdx.x;
  if (i < N_EDGES) atomicAdd(&deg[tgt[i]], 1);
}

__global__ __launch_bounds__(1024) void k_scan(const int* __restrict__ deg,
                                               int* __restrict__ offs,
                                               int* __restrict__ cursor) {
  __shared__ int wsum[16];
  __shared__ int carry_s;
  int lane = threadIdx.x & 63, wid = threadIdx.x >> 6;
  if (threadIdx.x == 0) { carry_s = 0; offs[0] = 0; }
  __syncthreads();
  for (int base = 0; base < N_NODES; base += 1024) {
    int i = base + threadIdx.x;
    int v = (i < N_NODES) ? deg[i] : 0;
    int x = v;
#pragma unroll
    for (int off = 1; off < 64; off <<= 1) {
      int t = __shfl_up(x, off, 64);
      if (lane >= off) x += t;
    }
    if (lane == 63) wsum[wid] = x;
    __syncthreads();
    if (wid == 0 && lane < 16) {
      int s = wsum[lane];
#pragma unroll
      for (int off = 1; off < 16; off <<= 1) {
        int t = __shfl_up(s, off, 64);
        if (lane >= off) s += t;
      }
      wsum[lane] = s;
    }
    __syncthreads();
    int add = (wid > 0 ? wsum[wid - 1] : 0) + carry_s;
    int incl = x + add;
    if (i < N_NODES) { offs[i + 1] = incl; cursor[i] = incl - v; }
    __syncthreads();
    if (threadIdx.x == 1023) carry_s = incl;
    __syncthreads();
  }
}

__global__ void k_scatter(const int* __restrict__ src, const int* __restrict__ tgt,
                          int* __restrict__ cursor, int* __restrict__ srcs,
                          int* __restrict__ eids) {
  int i = blockIdx.x * blockDim.x + threadIdx.x;
  if (i < N_EDGES) {
    int pos = atomicAdd(&cursor[tgt[i]], 1);
    srcs[pos] = src[i];
    eids[pos] = i;
  }
}

// Permute edge_attr into CSR order as fp16: eac[pos] = (fp16)ea[eids[pos]]
// 32 edges/block, 8 threads/edge (float4 read, half4 write).
__global__ __launch_bounds__(256) void k_perm_ea(const int* __restrict__ eids,
                                                 const float* __restrict__ ea,
                                                 _Float16* __restrict__ eac) {
  int i = blockIdx.x * 32 + (threadIdx.x >> 3);
  int c = (threadIdx.x & 7) * 4;
  if (i < N_EDGES) {
    float4 v = *(const float4*)&ea[(size_t)eids[i] * HID + c];
    half4v h = {(_Float16)v.x, (_Float16)v.y, (_Float16)v.z, (_Float16)v.w};
    *(half4v*)&eac[(size_t)i * HID + c] = h;
  }
}

// ---------------- conversions ----------------
// 8 elements per thread, half8 stores.
__global__ void k_conv_x(const float* __restrict__ x, _Float16* __restrict__ x16) {
  int i = blockIdx.x * 256 + threadIdx.x;
  if (i * 8 < N_NODES * HC) {
    float4 v0 = *(const float4*)&x[i * 8];
    float4 v1 = *(const float4*)&x[i * 8 + 4];
    half8 h = {(_Float16)v0.x, (_Float16)v0.y, (_Float16)v0.z, (_Float16)v0.w,
               (_Float16)v1.x, (_Float16)v1.y, (_Float16)v1.z, (_Float16)v1.w};
    *(half8*)&x16[i * 8] = h;
  }
}

// W^T packed [640 cols][128 k] fp16. Cols 0..511 here; 512..639 via k_fold_p.
__global__ __launch_bounds__(128) void k_conv_w(
    const float* __restrict__ wq, const float* __restrict__ wk,
    const float* __restrict__ wv, const float* __restrict__ ws,
    _Float16* __restrict__ wt) {
  int g = blockIdx.x;          // 0..511 global output col
  int k = threadIdx.x;         // 0..127
  const float* w = (g < 128) ? wq : (g < 256) ? wk : (g < 384) ? wv : ws;
  int c = g & 127;
  wt[g * HC + k] = (_Float16)w[k * HC + c];
}

// Fold p = q @ we^T into the node GEMM: wt cols 512..639 = wq @ W2, bp = bq @ W2
// where W2[f][c] = we[c&31][f] if same head else 0 (block-diagonal).
__global__ __launch_bounds__(128) void k_fold_p(const float* __restrict__ wq,
                                                const float* __restrict__ bq,
                                                const float* __restrict__ we,
                                                _Float16* __restrict__ wt,
                                                float* __restrict__ bp) {
  int c = blockIdx.x;          // 0..127 p-column
  int k = threadIdx.x;         // 0..127 input dim
  int hb = (c >> 5) << 5, j = c & 31;
  float s = 0.f;
#pragma unroll
  for (int d = 0; d < 32; ++d)
    s = fmaf(wq[k * HC + hb + d], we[j * HC + hb + d], s);
  wt[(size_t)(512 + c) * HC + k] = (_Float16)s;
  if (k == 0) {
    float b = 0.f;
    for (int d = 0; d < 32; ++d) b = fmaf(bq[hb + d], we[j * HC + hb + d], b);
    bp[c] = b;
  }
}

// ---------------- MFMA node GEMM (LDS-staged B) ----------------
// Grid (391 row-tiles, 5 matrices). Block = 4 waves x 32 rows = 128 rows x 128 cols.
// B-block (32KB) staged once into LDS, shared by all waves; A direct to regs.
// k (cb=1) and v (cb=2) write into interleaved kv[N][256]: k at +0, v at +128.
__global__ __launch_bounds__(256) void k_gemm(
    const _Float16* __restrict__ ain,   // [N][128] fp16
    const _Float16* __restrict__ wt,    // [640][128] fp16 = W^T
    const float* __restrict__ bq, const float* __restrict__ bk,
    const float* __restrict__ bv, const float* __restrict__ bs,
    const float* __restrict__ bp,
    __half* __restrict__ qn16, _Float16* __restrict__ kv16,
    float* __restrict__ sk, __half* __restrict__ p16) {
  __shared__ _Float16 Bs[128][132];    // +4 halves pad: ds_read 2-way (free)
  int tid = threadIdx.x;
  int wv = tid >> 6, lane = tid & 63;
  int quad = lane >> 4, l16 = lane & 15;
  int cb = blockIdx.y;                  // 0=q 1=k 2=v 3=skip 4=p

  // stage B: 2048 chunks of 16B; consecutive tid -> contiguous global reads
#pragma unroll
  for (int i = 0; i < 8; ++i) {
    int chunk = i * 256 + tid;
    int col = chunk >> 4, kc16 = chunk & 15;
    half8 b = *(const half8*)&wt[(size_t)(cb * 128 + col) * HC + kc16 * 8];
    *(half8*)&Bs[col][kc16 * 8] = b;
  }

  int r0 = blockIdx.x * 128 + wv * 32;
  half8 A[2][4];
#pragma unroll
  for (int m = 0; m < 2; ++m) {
    int arow = min(r0 + m * 16 + l16, N_NODES - 1);
#pragma unroll
    for (int kc = 0; kc < 4; ++kc)
      A[m][kc] = *(const half8*)&ain[(size_t)arow * HC + kc * 32 + quad * 8];
  }
  floatx4 acc[8][2];
#pragma unroll
  for (int ct = 0; ct < 8; ++ct) {
    acc[ct][0] = (floatx4){0.f, 0.f, 0.f, 0.f};
    acc[ct][1] = (floatx4){0.f, 0.f, 0.f, 0.f};
  }
  __syncthreads();

#pragma unroll
  for (int ct = 0; ct < 8; ++ct) {
#pragma unroll
    for (int kc = 0; kc < 4; ++kc) {
      half8 B = *(const half8*)&Bs[ct * 16 + l16][kc * 32 + quad * 8];
      acc[ct][0] = __builtin_amdgcn_mfma_f32_16x16x32_f16(A[0][kc], B, acc[ct][0], 0, 0, 0);
      acc[ct][1] = __builtin_amdgcn_mfma_f32_16x16x32_f16(A[1][kc], B, acc[ct][1], 0, 0, 0);
    }
  }

  const float* bias = (cb == 0) ? bq : (cb == 1) ? bk : (cb == 2) ? bv
                    : (cb == 3) ? bs : bp;
#pragma unroll
  for (int ct = 0; ct < 8; ++ct) {
    int lc = (ct << 4) + l16;
    float b = bias[lc];
#pragma unroll
    for (int m = 0; m < 2; ++m) {
#pragma unroll
      for (int reg = 0; reg < 4; ++reg) {
        int row = r0 + m * 16 + quad * 4 + reg;  // C/D: col=lane&15, row=quad*4+reg
        if (row < N_NODES) {
          float val = acc[ct][m][reg] + b;
          if (cb == 0) qn16[(size_t)row * HC + lc] = __float2half(val);
          else if (cb == 1) kv16[(size_t)row * 256 + lc] = (_Float16)val;
          else if (cb == 2) kv16[(size_t)row * 256 + 128 + lc] = (_Float16)val;
          else if (cb == 3) sk[(size_t)row * HC + lc] = val;
          else p16[(size_t)row * HC + lc] = __float2half(val);
        }
      }
    }
  }
}

// ---------------- edge attention ----------------
// One wave per target, 8 waves per block (512 threads) for occupancy.
// 4 edges in flight (16 lanes/edge, 8 feats/lane); interleaved kv[N][256];
// no online softmax (plain exp, fp32 accumulate); 2-deep K/V prefetch, 1-deep E.
__device__ __forceinline__ float dot8(half8 a, half8 b, float c) {
#if __has_builtin(__builtin_amdgcn_fdot2)
#pragma unroll
  for (int i = 0; i < 4; ++i) {
    half2v x = {a[2 * i], a[2 * i + 1]};
    half2v y = {b[2 * i], b[2 * i + 1]};
    c = __builtin_amdgcn_fdot2(x, y, c, false);
  }
#else
#pragma unroll
  for (int i = 0; i < 8; ++i) c = fmaf((float)a[i], (float)b[i], c);
#endif
  return c;
}

// sum over the 4 lanes of a quad via DPP quad_perm (xor1 then xor2)
__device__ __forceinline__ float quad_red(float x) {
  int b = __builtin_amdgcn_update_dpp(0, __float_as_int(x), 0xB1, 0xF, 0xF, true);
  float y = x + __int_as_float(b);
  int c2 = __builtin_amdgcn_update_dpp(0, __float_as_int(y), 0x4E, 0xF, 0xF, true);
  return y + __int_as_float(c2);
}

__global__ __launch_bounds__(512) void k_edge_attn(
    const int* __restrict__ offs, const int* __restrict__ srcs,
    const _Float16* __restrict__ eac,
    const _Float16* __restrict__ qn, const _Float16* __restrict__ kv,
    const float* __restrict__ sk,
    const _Float16* __restrict__ pn, const float* __restrict__ we,
    float* __restrict__ out, _Float16* __restrict__ o16) {
  int lane = threadIdx.x & 63;
  int wv_ = threadIdx.x >> 6;
  int t = blockIdx.x * TPB + wv_;
  int g = lane >> 4;          // edge subgroup 0..3
  int p = lane & 15;          // position within group
  int f0 = p << 3;            // feature base (8 feats, head = p>>2)
  int jd0 = (p & 3) << 3;     // ea-dim base (8 of 32 dims)

  half8 qh = *(const half8*)&qn[(size_t)t * HC + f0];
  half8 ph = *(const half8*)&pn[(size_t)t * HC + ((p >> 2) << 5) + jd0];

  int e0 = offs[t], e1 = offs[t + 1];
  const float inv_sqrt = 0.17677669529663687f;
  float den = 0.f;
  float acc[8], tac[8];
#pragma unroll
  for (int i = 0; i < 8; ++i) { acc[i] = 0.f; tac[i] = 0.f; }

  for (int base = e0; base < e1; base += 64) {
    int cnt = min(64, e1 - base);
    int sl = srcs[min(base + lane, e1 - 1)];
    int jc0 = min(g, cnt - 1);
    int jc1 = min(4 + g, cnt - 1);
    int s0 = __shfl(sl, jc0, 64);
    int s1 = __shfl(sl, jc1, 64);
    const _Float16* kv0 = &kv[(size_t)s0 * 256];
    const _Float16* kv1 = &kv[(size_t)s1 * 256];
    half8 K0 = *(const half8*)&kv0[f0];
    half8 V0 = *(const half8*)&kv0[128 + f0];
    half8 K1 = *(const half8*)&kv1[f0];
    half8 V1 = *(const half8*)&kv1[128 + f0];
    half8 E0 = *(const half8*)&eac[(size_t)(base + jc0) * HID + jd0];
    for (int jj = 0; jj < cnt; jj += 4) {
      // prefetch K/V for jj+8 (2-deep), E for jj+4 (1-deep)
      int jn2 = min(jj + 8 + g, cnt - 1);
      int sN = __shfl(sl, jn2, 64);
      const _Float16* kvN = &kv[(size_t)sN * 256];
      half8 KN = *(const half8*)&kvN[f0];
      half8 VN = *(const half8*)&kvN[128 + f0];
      int je = min(jj + 4 + g, cnt - 1);
      half8 EN = *(const half8*)&eac[(size_t)(base + je) * HID + jd0];

      float part = dot8(qh, K0, 0.f);
      part = dot8(ph, E0, part);
      part = quad_red(part);            // full 32-dim dot for this head
      float w = ((jj + g) < cnt) ? __expf(part * inv_sqrt) : 0.f;
      den += w;
#pragma unroll
      for (int i = 0; i < 8; ++i) {
        acc[i] = fmaf(w, (float)V0[i], acc[i]);
        tac[i] = fmaf(w, (float)E0[i], tac[i]);
      }
      K0 = K1; V0 = V1; E0 = EN;
      K1 = KN; V1 = VN;
    }
  }

  // merge the 4 edge-subgroups
#pragma unroll
  for (int i = 0; i < 8; ++i) {
    acc[i] += __shfl_xor(acc[i], 16, 64); acc[i] += __shfl_xor(acc[i], 32, 64);
    tac[i] += __shfl_xor(tac[i], 16, 64); tac[i] += __shfl_xor(tac[i], 32, 64);
  }
  den += __shfl_xor(den, 16, 64);
  den += __shfl_xor(den, 32, 64);

  // fx[f] = sum_j tac_h[j] * we[j][f]; j-range split across the 4 groups
  __shared__ float tl[TPB][16][9];
  if (g == 0) {
#pragma unroll
    for (int i = 0; i < 8; ++i) tl[wv_][p][i] = tac[i];
  }
  float fx[8];
#pragma unroll
  for (int i = 0; i < 8; ++i) fx[i] = 0.f;
  int r = (p & 12) + g;       // LDS row holding this head's j-range for group g
#pragma unroll
  for (int u = 0; u < 8; ++u) {
    float tv = tl[wv_][r][u];
    int j = (g << 3) + u;
    const float4* wr = (const float4*)&we[j * HC + f0];
    float4 w0 = wr[0], w1 = wr[1];
    fx[0] = fmaf(tv, w0.x, fx[0]); fx[1] = fmaf(tv, w0.y, fx[1]);
    fx[2] = fmaf(tv, w0.z, fx[2]); fx[3] = fmaf(tv, w0.w, fx[3]);
    fx[4] = fmaf(tv, w1.x, fx[4]); fx[5] = fmaf(tv, w1.y, fx[5]);
    fx[6] = fmaf(tv, w1.z, fx[6]); fx[7] = fmaf(tv, w1.w, fx[7]);
  }
#pragma unroll
  for (int i = 0; i < 8; ++i) {
    fx[i] += __shfl_xor(fx[i], 16, 64);
    fx[i] += __shfl_xor(fx[i], 32, 64);
  }

  if (g == 0) {
    float rd = (e1 > e0) ? (1.0f / den) : 0.f;
    const float4* skp = (const float4*)&sk[(size_t)t * HC + f0];
    float4 sa = skp[0], sb = skp[1];
    float o[8];
    o[0] = fmaf(acc[0] + fx[0], rd, sa.x);
    o[1] = fmaf(acc[1] + fx[1], rd, sa.y);
    o[2] = fmaf(acc[2] + fx[2], rd, sa.z);
    o[3] = fmaf(acc[3] + fx[3], rd, sa.w);
    o[4] = fmaf(acc[4] + fx[4], rd, sb.x);
    o[5] = fmaf(acc[5] + fx[5], rd, sb.y);
    o[6] = fmaf(acc[6] + fx[6], rd, sb.z);
    o[7] = fmaf(acc[7] + fx[7], rd, sb.w);
#pragma unroll
    for (int i = 0; i < 8; ++i) o[i] = o[i] > 0.f ? o[i] : __expf(o[i]) - 1.f;
    *(float4*)&out[(size_t)t * HC + f0] = (float4){o[0], o[1], o[2], o[3]};
    *(float4*)&out[(size_t)t * HC + f0 + 4] = (float4){o[4], o[5], o[6], o[7]};
    half8 v16 = {(_Float16)o[0], (_Float16)o[1], (_Float16)o[2], (_Float16)o[3],
                 (_Float16)o[4], (_Float16)o[5], (_Float16)o[6], (_Float16)o[7]};
    *(half8*)&o16[(size_t)t * HC + f0] = v16;
  }
}

// ---------------- global mean pool ----------------
__global__ __launch_bounds__(128) void k_pool_sum(const float* __restrict__ h,
                                                  const int* __restrict__ batch,
                                                  float* __restrict__ psum) {
  int c = threadIdx.x;
  int n0 = blockIdx.x * PNB;
  int n1 = n0 + PNB;
  float acc = 0.f;
  int curb = batch[n0];
  for (int n = n0; n < n1; ++n) {
    int b = batch[n];
    if (b != curb) {
      atomicAdd(&psum[curb * HC + c], acc);
      acc = 0.f;
      curb = b;
    }
    acc += h[n * HC + c];
  }
  atomicAdd(&psum[curb * HC + c], acc);
}

// ---------------- classifier + log_softmax ----------------
__global__ __launch_bounds__(1024) void k_classify(const float* __restrict__ psum,
                                                   const int* __restrict__ batch,
                                                   const float* __restrict__ wlin,
                                                   const float* __restrict__ blin,
                                                   float* __restrict__ out) {
  int tid = threadIdx.x;
  int b = tid >> 4, o = tid & 15;
  int lo = 0, hi = N_NODES;
  while (lo < hi) { int mid = (lo + hi) >> 1; if (batch[mid] < b) lo = mid + 1; else hi = mid; }
  int start = lo;
  lo = 0; hi = N_NODES;
  while (lo < hi) { int mid = (lo + hi) >> 1; if (batch[mid] <= b) lo = mid + 1; else hi = mid; }
  float cnt = fmaxf((float)(lo - start), 1.0f);
  float dot = 0.f;
  for (int d = 0; d < HC; ++d) dot = fmaf(psum[b * HC + d], wlin[d * OUT_C + o], dot);
  float acc = dot / cnt + blin[o];
  float mx = acc;
#pragma unroll
  for (int off = 8; off > 0; off >>= 1) mx = fmaxf(mx, __shfl_xor(mx, off, 64));
  float ex = __expf(acc - mx);
  float sum = ex;
#pragma unroll
  for (int off = 8; off > 0; off >>= 1) sum += __shfl_xor(sum, off, 64);
  out[tid] = acc - mx - logf(sum);
}

extern "C" void kernel_launch(void* const* d_in, const int* in_sizes, int n_in,
                              void* d_out, int out_size, void* d_ws, size_t ws_size,
                              hipStream_t stream) {
  const float* x = (const float*)d_in[0];
  const int* ei = (const int*)d_in[1];
  const float* ea = (const float*)d_in[2];
  const int* batch = (const int*)d_in[3];
  const float* wq1 = (const float*)d_in[4];  const float* bq1 = (const float*)d_in[5];
  const float* wk1 = (const float*)d_in[6];  const float* bk1 = (const float*)d_in[7];
  const float* wv1 = (const float*)d_in[8];  const float* bv1 = (const float*)d_in[9];
  const float* we1 = (const float*)d_in[10];
  const float* ws1 = (const float*)d_in[11]; const float* bs1 = (const float*)d_in[12];
  const float* wq2 = (const float*)d_in[13]; const float* bq2 = (const float*)d_in[14];
  const float* wk2 = (const float*)d_in[15]; const float* bk2 = (const float*)d_in[16];
  const float* wv2 = (const float*)d_in[17]; const float* bv2 = (const float*)d_in[18];
  const float* we2 = (const float*)d_in[19];
  const float* ws2 = (const float*)d_in[20]; const float* bs2 = (const float*)d_in[21];
  const float* wlin = (const float*)d_in[22]; const float* blin = (const float*)d_in[23];

  const int* srcI = ei;
  const int* tgtI = ei + N_EDGES;

  char* wsb = (char*)d_ws;
  size_t off = 0;
  auto alloc = [&](size_t bytes) -> void* {
    void* ptr = wsb + off;
    off += (bytes + 255) & ~(size_t)255;
    return ptr;
  };
  __half* qn16 = (__half*)alloc((size_t)N_NODES * HC * 2);
  _Float16* kv16 = (_Float16*)alloc((size_t)N_NODES * 256 * 2);  // interleaved k|v
  __half* p16  = (__half*)alloc((size_t)N_NODES * HC * 2);
  float* sk = (float*)alloc((size_t)N_NODES * HC * 4);
  float* h  = (float*)alloc((size_t)N_NODES * HC * 4);
  _Float16* in16 = (_Float16*)alloc((size_t)N_NODES * HC * 2);  // x16, then h16
  _Float16* wt1 = (_Float16*)alloc((size_t)640 * HC * 2);
  _Float16* wt2 = (_Float16*)alloc((size_t)640 * HC * 2);
  float* bp1 = (float*)alloc((size_t)HC * 4);
  float* bp2 = (float*)alloc((size_t)HC * 4);
  float* psum = (float*)alloc((size_t)NGRAPH * HC * 4);
  int* deg    = (int*)alloc((size_t)N_NODES * 4);
  int* offs   = (int*)alloc((size_t)(N_NODES + 1) * 4);
  int* cursor = (int*)alloc((size_t)N_NODES * 4);
  int* srcs   = (int*)alloc((size_t)N_EDGES * 4);
  int* eids   = (int*)alloc((size_t)N_EDGES * 4);
  _Float16* eac = (_Float16*)alloc((size_t)N_EDGES * HID * 2);

  // CSR build
  hipMemsetAsync(deg, 0, (size_t)N_NODES * 4, stream);
  k_hist<<<(N_EDGES + 255) / 256, 256, 0, stream>>>(tgtI, deg);
  k_scan<<<1, 1024, 0, stream>>>(deg, offs, cursor);
  k_scatter<<<(N_EDGES + 255) / 256, 256, 0, stream>>>(srcI, tgtI, cursor, srcs, eids);
  k_perm_ea<<<N_EDGES / 32, 256, 0, stream>>>(eids, ea, eac);

  // Conversions + weight packing
  k_conv_x<<<(N_NODES * HC / 8 + 255) / 256, 256, 0, stream>>>(x, in16);
  k_conv_w<<<512, 128, 0, stream>>>(wq1, wk1, wv1, ws1, wt1);
  k_conv_w<<<512, 128, 0, stream>>>(wq2, wk2, wv2, ws2, wt2);
  k_fold_p<<<128, 128, 0, stream>>>(wq1, bq1, we1, wt1, bp1);
  k_fold_p<<<128, 128, 0, stream>>>(wq2, bq2, we2, wt2, bp2);

  dim3 gemm_grid((N_NODES + 127) / 128, 5);
  // Layer 1
  k_gemm<<<gemm_grid, 256, 0, stream>>>(in16, wt1, bq1, bk1, bv1, bs1, bp1,
                                        qn16, kv16, sk, p16);
  k_edge_attn<<<N_NODES / TPB, 64 * TPB, 0, stream>>>(
      offs, srcs, eac, (const _Float16*)qn16, kv16, sk,
      (const _Float16*)p16, we1, h, in16);
  // Layer 2
  k_gemm<<<gemm_grid, 256, 0, stream>>>(in16, wt2, bq2, bk2, bv2, bs2, bp2,
                                        qn16, kv16, sk, p16);
  k_edge_attn<<<N_NODES / TPB, 64 * TPB, 0, stream>>>(
      offs, srcs, eac, (const _Float16*)qn16, kv16, sk,
      (const _Float16*)p16, we2, h, in16);

  // Pool + classify
  hipMemsetAsync(psum, 0, (size_t)NGRAPH * HC * 4, stream);
  k_pool_sum<<<N_NODES / PNB, 128, 0, stream>>>(h, batch, psum);
  k_classify<<<1, 1024, 0, stream>>>(psum, batch, wlin, blin, (float*)d_out);
}

// Round 10
// 704.888 us; speedup vs baseline: 1.0284x; 1.0284x over previous
//
#include <hip/hip_runtime.h>
#include <hip/hip_fp16.h>

#define N_NODES 50000
#define N_EDGES 800000
#define IN_C 128
#define HID 32
#define HC 128
#define OUT_C 16
#define NGRAPH 64
#define PNB 125  // nodes per block in pool
#define TPB 2    // targets (waves) per block in edge attn (8 regressed: r9)

typedef __attribute__((ext_vector_type(8))) _Float16 half8;
typedef __attribute__((ext_vector_type(4))) _Float16 half4v;
typedef __attribute__((ext_vector_type(2))) _Float16 half2v;
typedef __attribute__((ext_vector_type(4))) float floatx4;

// ---------------- CSR build ----------------
__global__ void k_hist(const int* __restrict__ tgt, int* __restrict__ deg) {
  int i = blockIdx.x * blockDim.x + threadIdx.x;
  if (i < N_EDGES) atomicAdd(&deg[tgt[i]], 1);
}

__global__ __launch_bounds__(1024) void k_scan(const int* __restrict__ deg,
                                               int* __restrict__ offs,
                                               int* __restrict__ cursor) {
  __shared__ int wsum[16];
  __shared__ int carry_s;
  int lane = threadIdx.x & 63, wid = threadIdx.x >> 6;
  if (threadIdx.x == 0) { carry_s = 0; offs[0] = 0; }
  __syncthreads();
  for (int base = 0; base < N_NODES; base += 1024) {
    int i = base + threadIdx.x;
    int v = (i < N_NODES) ? deg[i] : 0;
    int x = v;
#pragma unroll
    for (int off = 1; off < 64; off <<= 1) {
      int t = __shfl_up(x, off, 64);
      if (lane >= off) x += t;
    }
    if (lane == 63) wsum[wid] = x;
    __syncthreads();
    if (wid == 0 && lane < 16) {
      int s = wsum[lane];
#pragma unroll
      for (int off = 1; off < 16; off <<= 1) {
        int t = __shfl_up(s, off, 64);
        if (lane >= off) s += t;
      }
      wsum[lane] = s;
    }
    __syncthreads();
    int add = (wid > 0 ? wsum[wid - 1] : 0) + carry_s;
    int incl = x + add;
    if (i < N_NODES) { offs[i + 1] = incl; cursor[i] = incl - v; }
    __syncthreads();
    if (threadIdx.x == 1023) carry_s = incl;
    __syncthreads();
  }
}

__global__ void k_scatter(const int* __restrict__ src, const int* __restrict__ tgt,
                          int* __restrict__ cursor, int* __restrict__ srcs,
                          int* __restrict__ eids) {
  int i = blockIdx.x * blockDim.x + threadIdx.x;
  if (i < N_EDGES) {
    int pos = atomicAdd(&cursor[tgt[i]], 1);
    srcs[pos] = src[i];
    eids[pos] = i;
  }
}

// Permute edge_attr into CSR order as fp16: eac[pos] = (fp16)ea[eids[pos]]
__global__ __launch_bounds__(256) void k_perm_ea(const int* __restrict__ eids,
                                                 const float* __restrict__ ea,
                                                 _Float16* __restrict__ eac) {
  int i = blockIdx.x * 32 + (threadIdx.x >> 3);
  int c = (threadIdx.x & 7) * 4;
  if (i < N_EDGES) {
    float4 v = *(const float4*)&ea[(size_t)eids[i] * HID + c];
    half4v h = {(_Float16)v.x, (_Float16)v.y, (_Float16)v.z, (_Float16)v.w};
    *(half4v*)&eac[(size_t)i * HID + c] = h;
  }
}

// ---------------- conversions ----------------
__global__ void k_conv_x(const float* __restrict__ x, _Float16* __restrict__ x16) {
  int i = blockIdx.x * 256 + threadIdx.x;
  if (i * 8 < N_NODES * HC) {
    float4 v0 = *(const float4*)&x[i * 8];
    float4 v1 = *(const float4*)&x[i * 8 + 4];
    half8 h = {(_Float16)v0.x, (_Float16)v0.y, (_Float16)v0.z, (_Float16)v0.w,
               (_Float16)v1.x, (_Float16)v1.y, (_Float16)v1.z, (_Float16)v1.w};
    *(half8*)&x16[i * 8] = h;
  }
}

// W^T packed [640 cols][128 k] fp16. Cols 0..511 here; 512..639 via k_fold_p.
__global__ __launch_bounds__(128) void k_conv_w(
    const float* __restrict__ wq, const float* __restrict__ wk,
    const float* __restrict__ wv, const float* __restrict__ ws,
    _Float16* __restrict__ wt) {
  int g = blockIdx.x;          // 0..511 global output col
  int k = threadIdx.x;         // 0..127
  const float* w = (g < 128) ? wq : (g < 256) ? wk : (g < 384) ? wv : ws;
  int c = g & 127;
  wt[g * HC + k] = (_Float16)w[k * HC + c];
}

// Fold p = q @ we^T into the node GEMM: wt cols 512..639 = wq @ W2, bp = bq @ W2
__global__ __launch_bounds__(128) void k_fold_p(const float* __restrict__ wq,
                                                const float* __restrict__ bq,
                                                const float* __restrict__ we,
                                                _Float16* __restrict__ wt,
                                                float* __restrict__ bp) {
  int c = blockIdx.x;          // 0..127 p-column
  int k = threadIdx.x;         // 0..127 input dim
  int hb = (c >> 5) << 5, j = c & 31;
  float s = 0.f;
#pragma unroll
  for (int d = 0; d < 32; ++d)
    s = fmaf(wq[k * HC + hb + d], we[j * HC + hb + d], s);
  wt[(size_t)(512 + c) * HC + k] = (_Float16)s;
  if (k == 0) {
    float b = 0.f;
    for (int d = 0; d < 32; ++d) b = fmaf(bq[hb + d], we[j * HC + hb + d], b);
    bp[c] = b;
  }
}

// ---------------- MFMA node GEMM (LDS-staged B) ----------------
// k (cb=1) and v (cb=2) write into interleaved kv[N][256]: k at +0, v at +128.
__global__ __launch_bounds__(256) void k_gemm(
    const _Float16* __restrict__ ain,   // [N][128] fp16
    const _Float16* __restrict__ wt,    // [640][128] fp16 = W^T
    const float* __restrict__ bq, const float* __restrict__ bk,
    const float* __restrict__ bv, const float* __restrict__ bs,
    const float* __restrict__ bp,
    __half* __restrict__ qn16, _Float16* __restrict__ kv16,
    float* __restrict__ sk, __half* __restrict__ p16) {
  __shared__ _Float16 Bs[128][132];    // +4 halves pad: ds_read 2-way (free)
  int tid = threadIdx.x;
  int wv = tid >> 6, lane = tid & 63;
  int quad = lane >> 4, l16 = lane & 15;
  int cb = blockIdx.y;                  // 0=q 1=k 2=v 3=skip 4=p

#pragma unroll
  for (int i = 0; i < 8; ++i) {
    int chunk = i * 256 + tid;
    int col = chunk >> 4, kc16 = chunk & 15;
    half8 b = *(const half8*)&wt[(size_t)(cb * 128 + col) * HC + kc16 * 8];
    *(half8*)&Bs[col][kc16 * 8] = b;
  }

  int r0 = blockIdx.x * 128 + wv * 32;
  half8 A[2][4];
#pragma unroll
  for (int m = 0; m < 2; ++m) {
    int arow = min(r0 + m * 16 + l16, N_NODES - 1);
#pragma unroll
    for (int kc = 0; kc < 4; ++kc)
      A[m][kc] = *(const half8*)&ain[(size_t)arow * HC + kc * 32 + quad * 8];
  }
  floatx4 acc[8][2];
#pragma unroll
  for (int ct = 0; ct < 8; ++ct) {
    acc[ct][0] = (floatx4){0.f, 0.f, 0.f, 0.f};
    acc[ct][1] = (floatx4){0.f, 0.f, 0.f, 0.f};
  }
  __syncthreads();

#pragma unroll
  for (int ct = 0; ct < 8; ++ct) {
#pragma unroll
    for (int kc = 0; kc < 4; ++kc) {
      half8 B = *(const half8*)&Bs[ct * 16 + l16][kc * 32 + quad * 8];
      acc[ct][0] = __builtin_amdgcn_mfma_f32_16x16x32_f16(A[0][kc], B, acc[ct][0], 0, 0, 0);
      acc[ct][1] = __builtin_amdgcn_mfma_f32_16x16x32_f16(A[1][kc], B, acc[ct][1], 0, 0, 0);
    }
  }

  const float* bias = (cb == 0) ? bq : (cb == 1) ? bk : (cb == 2) ? bv
                    : (cb == 3) ? bs : bp;
#pragma unroll
  for (int ct = 0; ct < 8; ++ct) {
    int lc = (ct << 4) + l16;
    float b = bias[lc];
#pragma unroll
    for (int m = 0; m < 2; ++m) {
#pragma unroll
      for (int reg = 0; reg < 4; ++reg) {
        int row = r0 + m * 16 + quad * 4 + reg;  // C/D: col=lane&15, row=quad*4+reg
        if (row < N_NODES) {
          float val = acc[ct][m][reg] + b;
          if (cb == 0) qn16[(size_t)row * HC + lc] = __float2half(val);
          else if (cb == 1) kv16[(size_t)row * 256 + lc] = (_Float16)val;
          else if (cb == 2) kv16[(size_t)row * 256 + 128 + lc] = (_Float16)val;
          else if (cb == 3) sk[(size_t)row * HC + lc] = val;
          else p16[(size_t)row * HC + lc] = __float2half(val);
        }
      }
    }
  }
}

// ---------------- edge attention ----------------
// One wave per target. Per 16-edge chunk: each subgroup (16 lanes, 4 edges)
// loads ALL its K/V/E into registers up-front (12 independent loads in flight
// = one latency exposure), then computes the 4 edges from registers.
// Next chunk's srcs load is issued before the compute phase.
__device__ __forceinline__ float dot8(half8 a, half8 b, float c) {
#if __has_builtin(__builtin_amdgcn_fdot2)
#pragma unroll
  for (int i = 0; i < 4; ++i) {
    half2v x = {a[2 * i], a[2 * i + 1]};
    half2v y = {b[2 * i], b[2 * i + 1]};
    c = __builtin_amdgcn_fdot2(x, y, c, false);
  }
#else
#pragma unroll
  for (int i = 0; i < 8; ++i) c = fmaf((float)a[i], (float)b[i], c);
#endif
  return c;
}

// sum over the 4 lanes of a quad via DPP quad_perm (xor1 then xor2)
__device__ __forceinline__ float quad_red(float x) {
  int b = __builtin_amdgcn_update_dpp(0, __float_as_int(x), 0xB1, 0xF, 0xF, true);
  float y = x + __int_as_float(b);
  int c2 = __builtin_amdgcn_update_dpp(0, __float_as_int(y), 0x4E, 0xF, 0xF, true);
  return y + __int_as_float(c2);
}

__global__ __launch_bounds__(128) void k_edge_attn(
    const int* __restrict__ offs, const int* __restrict__ srcs,
    const _Float16* __restrict__ eac,
    const _Float16* __restrict__ qn, const _Float16* __restrict__ kv,
    const float* __restrict__ sk,
    const _Float16* __restrict__ pn, const float* __restrict__ we,
    float* __restrict__ out, _Float16* __restrict__ o16) {
  int lane = threadIdx.x & 63;
  int wv_ = threadIdx.x >> 6;
  int t = blockIdx.x * TPB + wv_;
  int g = lane >> 4;          // edge subgroup 0..3
  int p = lane & 15;          // position within group
  int f0 = p << 3;            // feature base (8 feats, head = p>>2)
  int jd0 = (p & 3) << 3;     // ea-dim base (8 of 32 dims)

  half8 qh = *(const half8*)&qn[(size_t)t * HC + f0];
  half8 ph = *(const half8*)&pn[(size_t)t * HC + ((p >> 2) << 5) + jd0];

  int e0 = offs[t], e1 = offs[t + 1];
  const float inv_sqrt = 0.17677669529663687f;
  float den = 0.f;
  float acc[8], tac[8];
#pragma unroll
  for (int i = 0; i < 8; ++i) { acc[i] = 0.f; tac[i] = 0.f; }

  int sl = (e0 < e1) ? srcs[min(e0 + (lane & 15), e1 - 1)] : 0;
  for (int base = e0; base < e1; base += 16) {
    int cnt = e1 - base;               // remaining edges (>0)
    // ---- gather phase: 12 independent loads, all in flight at once ----
    half8 K[4], V[4], E[4];
#pragma unroll
    for (int i = 0; i < 4; ++i) {
      int j = 4 * g + i;
      int jc = min(j, cnt - 1);
      int s = __shfl(sl, jc, 64);
      const _Float16* kvp = &kv[(size_t)s * 256];
      K[i] = *(const half8*)&kvp[f0];
      V[i] = *(const half8*)&kvp[128 + f0];
      E[i] = *(const half8*)&eac[(size_t)(base + jc) * HID + jd0];
    }
    // issue next chunk's srcs load under the compute phase
    int nb = base + 16;
    int sl_n = (nb < e1) ? srcs[min(nb + (lane & 15), e1 - 1)] : 0;
    // ---- compute phase: 4 edges from registers ----
#pragma unroll
    for (int i = 0; i < 4; ++i) {
      int j = 4 * g + i;
      float part = dot8(qh, K[i], 0.f);
      part = dot8(ph, E[i], part);
      part = quad_red(part);           // full 32-dim dot for this head
      float w = (j < cnt) ? __expf(part * inv_sqrt) : 0.f;
      den += w;
#pragma unroll
      for (int q2 = 0; q2 < 8; ++q2) {
        acc[q2] = fmaf(w, (float)V[i][q2], acc[q2]);
        tac[q2] = fmaf(w, (float)E[i][q2], tac[q2]);
      }
    }
    sl = sl_n;
  }

  // merge the 4 edge-subgroups
#pragma unroll
  for (int i = 0; i < 8; ++i) {
    acc[i] += __shfl_xor(acc[i], 16, 64); acc[i] += __shfl_xor(acc[i], 32, 64);
    tac[i] += __shfl_xor(tac[i], 16, 64); tac[i] += __shfl_xor(tac[i], 32, 64);
  }
  den += __shfl_xor(den, 16, 64);
  den += __shfl_xor(den, 32, 64);

  // fx[f] = sum_j tac_h[j] * we[j][f]; j-range split across the 4 groups
  __shared__ float tl[TPB][16][9];
  if (g == 0) {
#pragma unroll
    for (int i = 0; i < 8; ++i) tl[wv_][p][i] = tac[i];
  }
  float fx[8];
#pragma unroll
  for (int i = 0; i < 8; ++i) fx[i] = 0.f;
  int r = (p & 12) + g;       // LDS row holding this head's j-range for group g
#pragma unroll
  for (int u = 0; u < 8; ++u) {
    float tv = tl[wv_][r][u];
    int j = (g << 3) + u;
    const float4* wr = (const float4*)&we[j * HC + f0];
    float4 w0 = wr[0], w1 = wr[1];
    fx[0] = fmaf(tv, w0.x, fx[0]); fx[1] = fmaf(tv, w0.y, fx[1]);
    fx[2] = fmaf(tv, w0.z, fx[2]); fx[3] = fmaf(tv, w0.w, fx[3]);
    fx[4] = fmaf(tv, w1.x, fx[4]); fx[5] = fmaf(tv, w1.y, fx[5]);
    fx[6] = fmaf(tv, w1.z, fx[6]); fx[7] = fmaf(tv, w1.w, fx[7]);
  }
#pragma unroll
  for (int i = 0; i < 8; ++i) {
    fx[i] += __shfl_xor(fx[i], 16, 64);
    fx[i] += __shfl_xor(fx[i], 32, 64);
  }

  if (g == 0) {
    float rd = (e1 > e0) ? (1.0f / den) : 0.f;
    const float4* skp = (const float4*)&sk[(size_t)t * HC + f0];
    float4 sa = skp[0], sb = skp[1];
    float o[8];
    o[0] = fmaf(acc[0] + fx[0], rd, sa.x);
    o[1] = fmaf(acc[1] + fx[1], rd, sa.y);
    o[2] = fmaf(acc[2] + fx[2], rd, sa.z);
    o[3] = fmaf(acc[3] + fx[3], rd, sa.w);
    o[4] = fmaf(acc[4] + fx[4], rd, sb.x);
    o[5] = fmaf(acc[5] + fx[5], rd, sb.y);
    o[6] = fmaf(acc[6] + fx[6], rd, sb.z);
    o[7] = fmaf(acc[7] + fx[7], rd, sb.w);
#pragma unroll
    for (int i = 0; i < 8; ++i) o[i] = o[i] > 0.f ? o[i] : __expf(o[i]) - 1.f;
    *(float4*)&out[(size_t)t * HC + f0] = (float4){o[0], o[1], o[2], o[3]};
    *(float4*)&out[(size_t)t * HC + f0 + 4] = (float4){o[4], o[5], o[6], o[7]};
    half8 v16 = {(_Float16)o[0], (_Float16)o[1], (_Float16)o[2], (_Float16)o[3],
                 (_Float16)o[4], (_Float16)o[5], (_Float16)o[6], (_Float16)o[7]};
    *(half8*)&o16[(size_t)t * HC + f0] = v16;
  }
}

// ---------------- global mean pool ----------------
__global__ __launch_bounds__(128) void k_pool_sum(const float* __restrict__ h,
                                                  const int* __restrict__ batch,
                                                  float* __restrict__ psum) {
  int c = threadIdx.x;
  int n0 = blockIdx.x * PNB;
  int n1 = n0 + PNB;
  float acc = 0.f;
  int curb = batch[n0];
  for (int n = n0; n < n1; ++n) {
    int b = batch[n];
    if (b != curb) {
      atomicAdd(&psum[curb * HC + c], acc);
      acc = 0.f;
      curb = b;
    }
    acc += h[n * HC + c];
  }
  atomicAdd(&psum[curb * HC + c], acc);
}

// ---------------- classifier + log_softmax ----------------
__global__ __launch_bounds__(1024) void k_classify(const float* __restrict__ psum,
                                                   const int* __restrict__ batch,
                                                   const float* __restrict__ wlin,
                                                   const float* __restrict__ blin,
                                                   float* __restrict__ out) {
  int tid = threadIdx.x;
  int b = tid >> 4, o = tid & 15;
  int lo = 0, hi = N_NODES;
  while (lo < hi) { int mid = (lo + hi) >> 1; if (batch[mid] < b) lo = mid + 1; else hi = mid; }
  int start = lo;
  lo = 0; hi = N_NODES;
  while (lo < hi) { int mid = (lo + hi) >> 1; if (batch[mid] <= b) lo = mid + 1; else hi = mid; }
  float cnt = fmaxf((float)(lo - start), 1.0f);
  float dot = 0.f;
  for (int d = 0; d < HC; ++d) dot = fmaf(psum[b * HC + d], wlin[d * OUT_C + o], dot);
  float acc = dot / cnt + blin[o];
  float mx = acc;
#pragma unroll
  for (int off = 8; off > 0; off >>= 1) mx = fmaxf(mx, __shfl_xor(mx, off, 64));
  float ex = __expf(acc - mx);
  float sum = ex;
#pragma unroll
  for (int off = 8; off > 0; off >>= 1) sum += __shfl_xor(sum, off, 64);
  out[tid] = acc - mx - logf(sum);
}

extern "C" void kernel_launch(void* const* d_in, const int* in_sizes, int n_in,
                              void* d_out, int out_size, void* d_ws, size_t ws_size,
                              hipStream_t stream) {
  const float* x = (const float*)d_in[0];
  const int* ei = (const int*)d_in[1];
  const float* ea = (const float*)d_in[2];
  const int* batch = (const int*)d_in[3];
  const float* wq1 = (const float*)d_in[4];  const float* bq1 = (const float*)d_in[5];
  const float* wk1 = (const float*)d_in[6];  const float* bk1 = (const float*)d_in[7];
  const float* wv1 = (const float*)d_in[8];  const float* bv1 = (const float*)d_in[9];
  const float* we1 = (const float*)d_in[10];
  const float* ws1 = (const float*)d_in[11]; const float* bs1 = (const float*)d_in[12];
  const float* wq2 = (const float*)d_in[13]; const float* bq2 = (const float*)d_in[14];
  const float* wk2 = (const float*)d_in[15]; const float* bk2 = (const float*)d_in[16];
  const float* wv2 = (const float*)d_in[17]; const float* bv2 = (const float*)d_in[18];
  const float* we2 = (const float*)d_in[19];
  const float* ws2 = (const float*)d_in[20]; const float* bs2 = (const float*)d_in[21];
  const float* wlin = (const float*)d_in[22]; const float* blin = (const float*)d_in[23];

  const int* srcI = ei;
  const int* tgtI = ei + N_EDGES;

  char* wsb = (char*)d_ws;
  size_t off = 0;
  auto alloc = [&](size_t bytes) -> void* {
    void* ptr = wsb + off;
    off += (bytes + 255) & ~(size_t)255;
    return ptr;
  };
  __half* qn16 = (__half*)alloc((size_t)N_NODES * HC * 2);
  _Float16* kv16 = (_Float16*)alloc((size_t)N_NODES * 256 * 2);  // interleaved k|v
  __half* p16  = (__half*)alloc((size_t)N_NODES * HC * 2);
  float* sk = (float*)alloc((size_t)N_NODES * HC * 4);
  float* h  = (float*)alloc((size_t)N_NODES * HC * 4);
  _Float16* in16 = (_Float16*)alloc((size_t)N_NODES * HC * 2);  // x16, then h16
  _Float16* wt1 = (_Float16*)alloc((size_t)640 * HC * 2);
  _Float16* wt2 = (_Float16*)alloc((size_t)640 * HC * 2);
  float* bp1 = (float*)alloc((size_t)HC * 4);
  float* bp2 = (float*)alloc((size_t)HC * 4);
  float* psum = (float*)alloc((size_t)NGRAPH * HC * 4);
  int* deg    = (int*)alloc((size_t)N_NODES * 4);
  int* offs   = (int*)alloc((size_t)(N_NODES + 1) * 4);
  int* cursor = (int*)alloc((size_t)N_NODES * 4);
  int* srcs   = (int*)alloc((size_t)N_EDGES * 4);
  int* eids   = (int*)alloc((size_t)N_EDGES * 4);
  _Float16* eac = (_Float16*)alloc((size_t)N_EDGES * HID * 2);

  // CSR build
  hipMemsetAsync(deg, 0, (size_t)N_NODES * 4, stream);
  k_hist<<<(N_EDGES + 255) / 256, 256, 0, stream>>>(tgtI, deg);
  k_scan<<<1, 1024, 0, stream>>>(deg, offs, cursor);
  k_scatter<<<(N_EDGES + 255) / 256, 256, 0, stream>>>(srcI, tgtI, cursor, srcs, eids);
  k_perm_ea<<<N_EDGES / 32, 256, 0, stream>>>(eids, ea, eac);

  // Conversions + weight packing
  k_conv_x<<<(N_NODES * HC / 8 + 255) / 256, 256, 0, stream>>>(x, in16);
  k_conv_w<<<512, 128, 0, stream>>>(wq1, wk1, wv1, ws1, wt1);
  k_conv_w<<<512, 128, 0, stream>>>(wq2, wk2, wv2, ws2, wt2);
  k_fold_p<<<128, 128, 0, stream>>>(wq1, bq1, we1, wt1, bp1);
  k_fold_p<<<128, 128, 0, stream>>>(wq2, bq2, we2, wt2, bp2);

  dim3 gemm_grid((N_NODES + 127) / 128, 5);
  // Layer 1
  k_gemm<<<gemm_grid, 256, 0, stream>>>(in16, wt1, bq1, bk1, bv1, bs1, bp1,
                                        qn16, kv16, sk, p16);
  k_edge_attn<<<N_NODES / TPB, 64 * TPB, 0, stream>>>(
      offs, srcs, eac, (const _Float16*)qn16, kv16, sk,
      (const _Float16*)p16, we1, h, in16);
  // Layer 2
  k_gemm<<<gemm_grid, 256, 0, stream>>>(in16, wt2, bq2, bk2, bv2, bs2, bp2,
                                        qn16, kv16, sk, p16);
  k_edge_attn<<<N_NODES / TPB, 64 * TPB, 0, stream>>>(
      offs, srcs, eac, (const _Float16*)qn16, kv16, sk,
      (const _Float16*)p16, we2, h, in16);

  // Pool + classify
  hipMemsetAsync(psum, 0, (size_t)NGRAPH * HC * 4, stream);
  k_pool_sum<<<N_NODES / PNB, 128, 0, stream>>>(h, batch, psum);
  k_classify<<<1, 1024, 0, stream>>>(psum, batch, wlin, blin, (float*)d_out);
}

// Round 16
// 662.327 us; speedup vs baseline: 1.0945x; 1.0643x over previous
//
#include <hip/hip_runtime.h>
#include <hip/hip_fp16.h>

#define N_NODES 50000
#define N_EDGES 800000
#define IN_C 128
#define HID 32
#define HC 128
#define OUT_C 16
#define NGRAPH 64
#define PNB 125  // nodes per block in pool
#define TPB 2    // targets (waves) per block in edge attn

typedef __attribute__((ext_vector_type(8))) _Float16 half8;
typedef __attribute__((ext_vector_type(4))) _Float16 half4v;
typedef __attribute__((ext_vector_type(2))) _Float16 half2v;
typedef __attribute__((ext_vector_type(4))) float floatx4;

// ---------------- CSR build ----------------
__global__ void k_hist(const int* __restrict__ tgt, int* __restrict__ deg) {
  int i = blockIdx.x * blockDim.x + threadIdx.x;
  if (i < N_EDGES) atomicAdd(&deg[tgt[i]], 1);
}

__global__ __launch_bounds__(1024) void k_scan(const int* __restrict__ deg,
                                               int* __restrict__ offs,
                                               int* __restrict__ cursor) {
  __shared__ int wsum[16];
  __shared__ int carry_s;
  int lane = threadIdx.x & 63, wid = threadIdx.x >> 6;
  if (threadIdx.x == 0) { carry_s = 0; offs[0] = 0; }
  __syncthreads();
  for (int base = 0; base < N_NODES; base += 1024) {
    int i = base + threadIdx.x;
    int v = (i < N_NODES) ? deg[i] : 0;
    int x = v;
#pragma unroll
    for (int off = 1; off < 64; off <<= 1) {
      int t = __shfl_up(x, off, 64);
      if (lane >= off) x += t;
    }
    if (lane == 63) wsum[wid] = x;
    __syncthreads();
    if (wid == 0 && lane < 16) {
      int s = wsum[lane];
#pragma unroll
      for (int off = 1; off < 16; off <<= 1) {
        int t = __shfl_up(s, off, 64);
        if (lane >= off) s += t;
      }
      wsum[lane] = s;
    }
    __syncthreads();
    int add = (wid > 0 ? wsum[wid - 1] : 0) + carry_s;
    int incl = x + add;
    if (i < N_NODES) { offs[i + 1] = incl; cursor[i] = incl - v; }
    __syncthreads();
    if (threadIdx.x == 1023) carry_s = incl;
    __syncthreads();
  }
}

// Fused scatter: build srcs[] AND permute edge_attr into CSR order as fp16.
// 8 lanes per edge; leader does the atomic, pos broadcast via shfl; the 8
// lanes then move the 32-float row as coalesced 16B reads / 128B-line writes.
__global__ __launch_bounds__(256) void k_scatter(
    const int* __restrict__ src, const int* __restrict__ tgt,
    int* __restrict__ cursor, const float* __restrict__ ea,
    int* __restrict__ srcs, _Float16* __restrict__ eac) {
  int i = blockIdx.x * 32 + (threadIdx.x >> 3);
  int c = threadIdx.x & 7;
  int lane = threadIdx.x & 63;
  int pos = 0;
  if (c == 0) pos = atomicAdd(&cursor[tgt[i]], 1);
  pos = __shfl(pos, lane & 0x38, 64);   // broadcast from group leader
  if (c == 0) srcs[pos] = src[i];
  float4 v = *(const float4*)&ea[(size_t)i * HID + c * 4];
  half4v h = {(_Float16)v.x, (_Float16)v.y, (_Float16)v.z, (_Float16)v.w};
  *(half4v*)&eac[(size_t)pos * HID + c * 4] = h;
}

// ---------------- conversions ----------------
__global__ void k_conv_x(const float* __restrict__ x, _Float16* __restrict__ x16) {
  int i = blockIdx.x * 256 + threadIdx.x;
  if (i * 8 < N_NODES * HC) {
    float4 v0 = *(const float4*)&x[i * 8];
    float4 v1 = *(const float4*)&x[i * 8 + 4];
    half8 h = {(_Float16)v0.x, (_Float16)v0.y, (_Float16)v0.z, (_Float16)v0.w,
               (_Float16)v1.x, (_Float16)v1.y, (_Float16)v1.z, (_Float16)v1.w};
    *(half8*)&x16[i * 8] = h;
  }
}

// W^T packed [640 cols][128 k] fp16. Cols 0..511 here; 512..639 via k_fold_p.
__global__ __launch_bounds__(128) void k_conv_w(
    const float* __restrict__ wq, const float* __restrict__ wk,
    const float* __restrict__ wv, const float* __restrict__ ws,
    _Float16* __restrict__ wt) {
  int g = blockIdx.x;          // 0..511 global output col
  int k = threadIdx.x;         // 0..127
  const float* w = (g < 128) ? wq : (g < 256) ? wk : (g < 384) ? wv : ws;
  int c = g & 127;
  wt[g * HC + k] = (_Float16)w[k * HC + c];
}

// Fold p = q @ we^T into the node GEMM: wt cols 512..639 = wq @ W2, bp = bq @ W2
__global__ __launch_bounds__(128) void k_fold_p(const float* __restrict__ wq,
                                                const float* __restrict__ bq,
                                                const float* __restrict__ we,
                                                _Float16* __restrict__ wt,
                                                float* __restrict__ bp) {
  int c = blockIdx.x;          // 0..127 p-column
  int k = threadIdx.x;         // 0..127 input dim
  int hb = (c >> 5) << 5, j = c & 31;
  float s = 0.f;
#pragma unroll
  for (int d = 0; d < 32; ++d)
    s = fmaf(wq[k * HC + hb + d], we[j * HC + hb + d], s);
  wt[(size_t)(512 + c) * HC + k] = (_Float16)s;
  if (k == 0) {
    float b = 0.f;
    for (int d = 0; d < 32; ++d) b = fmaf(bq[hb + d], we[j * HC + hb + d], b);
    bp[c] = b;
  }
}

// ---------------- MFMA node GEMM (LDS-staged B) ----------------
// k (cb=1) and v (cb=2) write into interleaved kv[N][256]: k at +0, v at +128.
// skip (cb=3) now stored fp16.
__global__ __launch_bounds__(256) void k_gemm(
    const _Float16* __restrict__ ain,   // [N][128] fp16
    const _Float16* __restrict__ wt,    // [640][128] fp16 = W^T
    const float* __restrict__ bq, const float* __restrict__ bk,
    const float* __restrict__ bv, const float* __restrict__ bs,
    const float* __restrict__ bp,
    __half* __restrict__ qn16, _Float16* __restrict__ kv16,
    _Float16* __restrict__ sk16, __half* __restrict__ p16) {
  __shared__ _Float16 Bs[128][132];    // +4 halves pad: ds_read 2-way (free)
  int tid = threadIdx.x;
  int wv = tid >> 6, lane = tid & 63;
  int quad = lane >> 4, l16 = lane & 15;
  int cb = blockIdx.y;                  // 0=q 1=k 2=v 3=skip 4=p

#pragma unroll
  for (int i = 0; i < 8; ++i) {
    int chunk = i * 256 + tid;
    int col = chunk >> 4, kc16 = chunk & 15;
    half8 b = *(const half8*)&wt[(size_t)(cb * 128 + col) * HC + kc16 * 8];
    *(half8*)&Bs[col][kc16 * 8] = b;
  }

  int r0 = blockIdx.x * 128 + wv * 32;
  half8 A[2][4];
#pragma unroll
  for (int m = 0; m < 2; ++m) {
    int arow = min(r0 + m * 16 + l16, N_NODES - 1);
#pragma unroll
    for (int kc = 0; kc < 4; ++kc)
      A[m][kc] = *(const half8*)&ain[(size_t)arow * HC + kc * 32 + quad * 8];
  }
  floatx4 acc[8][2];
#pragma unroll
  for (int ct = 0; ct < 8; ++ct) {
    acc[ct][0] = (floatx4){0.f, 0.f, 0.f, 0.f};
    acc[ct][1] = (floatx4){0.f, 0.f, 0.f, 0.f};
  }
  __syncthreads();

#pragma unroll
  for (int ct = 0; ct < 8; ++ct) {
#pragma unroll
    for (int kc = 0; kc < 4; ++kc) {
      half8 B = *(const half8*)&Bs[ct * 16 + l16][kc * 32 + quad * 8];
      acc[ct][0] = __builtin_amdgcn_mfma_f32_16x16x32_f16(A[0][kc], B, acc[ct][0], 0, 0, 0);
      acc[ct][1] = __builtin_amdgcn_mfma_f32_16x16x32_f16(A[1][kc], B, acc[ct][1], 0, 0, 0);
    }
  }

  const float* bias = (cb == 0) ? bq : (cb == 1) ? bk : (cb == 2) ? bv
                    : (cb == 3) ? bs : bp;
#pragma unroll
  for (int ct = 0; ct < 8; ++ct) {
    int lc = (ct << 4) + l16;
    float b = bias[lc];
#pragma unroll
    for (int m = 0; m < 2; ++m) {
#pragma unroll
      for (int reg = 0; reg < 4; ++reg) {
        int row = r0 + m * 16 + quad * 4 + reg;  // C/D: col=lane&15, row=quad*4+reg
        if (row < N_NODES) {
          float val = acc[ct][m][reg] + b;
          if (cb == 0) qn16[(size_t)row * HC + lc] = __float2half(val);
          else if (cb == 1) kv16[(size_t)row * 256 + lc] = (_Float16)val;
          else if (cb == 2) kv16[(size_t)row * 256 + 128 + lc] = (_Float16)val;
          else if (cb == 3) sk16[(size_t)row * HC + lc] = (_Float16)val;
          else p16[(size_t)row * HC + lc] = __float2half(val);
        }
      }
    }
  }
}

// ---------------- edge attention ----------------
// One wave per target. Per 16-edge chunk: batch-gather K/V/E to registers
// (12 independent loads = one latency exposure), compute from registers.
// fp16 skip input; writes ONLY fp16 output (pool reads fp16).
__device__ __forceinline__ float dot8(half8 a, half8 b, float c) {
#if __has_builtin(__builtin_amdgcn_fdot2)
#pragma unroll
  for (int i = 0; i < 4; ++i) {
    half2v x = {a[2 * i], a[2 * i + 1]};
    half2v y = {b[2 * i], b[2 * i + 1]};
    c = __builtin_amdgcn_fdot2(x, y, c, false);
  }
#else
#pragma unroll
  for (int i = 0; i < 8; ++i) c = fmaf((float)a[i], (float)b[i], c);
#endif
  return c;
}

// sum over the 4 lanes of a quad via DPP quad_perm (xor1 then xor2)
__device__ __forceinline__ float quad_red(float x) {
  int b = __builtin_amdgcn_update_dpp(0, __float_as_int(x), 0xB1, 0xF, 0xF, true);
  float y = x + __int_as_float(b);
  int c2 = __builtin_amdgcn_update_dpp(0, __float_as_int(y), 0x4E, 0xF, 0xF, true);
  return y + __int_as_float(c2);
}

__global__ __launch_bounds__(128) void k_edge_attn(
    const int* __restrict__ offs, const int* __restrict__ srcs,
    const _Float16* __restrict__ eac,
    const _Float16* __restrict__ qn, const _Float16* __restrict__ kv,
    const _Float16* __restrict__ sk,
    const _Float16* __restrict__ pn, const float* __restrict__ we,
    _Float16* __restrict__ o16) {
  int lane = threadIdx.x & 63;
  int wv_ = threadIdx.x >> 6;
  int t = blockIdx.x * TPB + wv_;
  int g = lane >> 4;          // edge subgroup 0..3
  int p = lane & 15;          // position within group
  int f0 = p << 3;            // feature base (8 feats, head = p>>2)
  int jd0 = (p & 3) << 3;     // ea-dim base (8 of 32 dims)

  half8 qh = *(const half8*)&qn[(size_t)t * HC + f0];
  half8 ph = *(const half8*)&pn[(size_t)t * HC + ((p >> 2) << 5) + jd0];

  int e0 = offs[t], e1 = offs[t + 1];
  const float inv_sqrt = 0.17677669529663687f;
  float den = 0.f;
  float acc[8], tac[8];
#pragma unroll
  for (int i = 0; i < 8; ++i) { acc[i] = 0.f; tac[i] = 0.f; }

  int sl = (e0 < e1) ? srcs[min(e0 + (lane & 15), e1 - 1)] : 0;
  for (int base = e0; base < e1; base += 16) {
    int cnt = e1 - base;               // remaining edges (>0)
    // ---- gather phase: 12 independent loads, all in flight at once ----
    half8 K[4], V[4], E[4];
#pragma unroll
    for (int i = 0; i < 4; ++i) {
      int j = 4 * g + i;
      int jc = min(j, cnt - 1);
      int s = __shfl(sl, jc, 64);
      const _Float16* kvp = &kv[(size_t)s * 256];
      K[i] = *(const half8*)&kvp[f0];
      V[i] = *(const half8*)&kvp[128 + f0];
      E[i] = *(const half8*)&eac[(size_t)(base + jc) * HID + jd0];
    }
    // issue next chunk's srcs load under the compute phase
    int nb = base + 16;
    int sl_n = (nb < e1) ? srcs[min(nb + (lane & 15), e1 - 1)] : 0;
    // ---- compute phase: 4 edges from registers ----
#pragma unroll
    for (int i = 0; i < 4; ++i) {
      int j = 4 * g + i;
      float part = dot8(qh, K[i], 0.f);
      part = dot8(ph, E[i], part);
      part = quad_red(part);           // full 32-dim dot for this head
      float w = (j < cnt) ? __expf(part * inv_sqrt) : 0.f;
      den += w;
#pragma unroll
      for (int q2 = 0; q2 < 8; ++q2) {
        acc[q2] = fmaf(w, (float)V[i][q2], acc[q2]);
        tac[q2] = fmaf(w, (float)E[i][q2], tac[q2]);
      }
    }
    sl = sl_n;
  }

  // merge the 4 edge-subgroups
#pragma unroll
  for (int i = 0; i < 8; ++i) {
    acc[i] += __shfl_xor(acc[i], 16, 64); acc[i] += __shfl_xor(acc[i], 32, 64);
    tac[i] += __shfl_xor(tac[i], 16, 64); tac[i] += __shfl_xor(tac[i], 32, 64);
  }
  den += __shfl_xor(den, 16, 64);
  den += __shfl_xor(den, 32, 64);

  // fx[f] = sum_j tac_h[j] * we[j][f]; j-range split across the 4 groups
  __shared__ float tl[TPB][16][9];
  if (g == 0) {
#pragma unroll
    for (int i = 0; i < 8; ++i) tl[wv_][p][i] = tac[i];
  }
  float fx[8];
#pragma unroll
  for (int i = 0; i < 8; ++i) fx[i] = 0.f;
  int r = (p & 12) + g;       // LDS row holding this head's j-range for group g
#pragma unroll
  for (int u = 0; u < 8; ++u) {
    float tv = tl[wv_][r][u];
    int j = (g << 3) + u;
    const float4* wr = (const float4*)&we[j * HC + f0];
    float4 w0 = wr[0], w1 = wr[1];
    fx[0] = fmaf(tv, w0.x, fx[0]); fx[1] = fmaf(tv, w0.y, fx[1]);
    fx[2] = fmaf(tv, w0.z, fx[2]); fx[3] = fmaf(tv, w0.w, fx[3]);
    fx[4] = fmaf(tv, w1.x, fx[4]); fx[5] = fmaf(tv, w1.y, fx[5]);
    fx[6] = fmaf(tv, w1.z, fx[6]); fx[7] = fmaf(tv, w1.w, fx[7]);
  }
#pragma unroll
  for (int i = 0; i < 8; ++i) {
    fx[i] += __shfl_xor(fx[i], 16, 64);
    fx[i] += __shfl_xor(fx[i], 32, 64);
  }

  if (g == 0) {
    float rd = (e1 > e0) ? (1.0f / den) : 0.f;
    half8 s8 = *(const half8*)&sk[(size_t)t * HC + f0];
    float o[8];
#pragma unroll
    for (int i = 0; i < 8; ++i) {
      o[i] = fmaf(acc[i] + fx[i], rd, (float)s8[i]);
      o[i] = o[i] > 0.f ? o[i] : __expf(o[i]) - 1.f;
    }
    half8 v16 = {(_Float16)o[0], (_Float16)o[1], (_Float16)o[2], (_Float16)o[3],
                 (_Float16)o[4], (_Float16)o[5], (_Float16)o[6], (_Float16)o[7]};
    *(half8*)&o16[(size_t)t * HC + f0] = v16;
  }
}

// ---------------- global mean pool (reads fp16 h) ----------------
__global__ __launch_bounds__(128) void k_pool_sum(const _Float16* __restrict__ h16,
                                                  const int* __restrict__ batch,
                                                  float* __restrict__ psum) {
  int c = threadIdx.x;
  int n0 = blockIdx.x * PNB;
  int n1 = n0 + PNB;
  float acc = 0.f;
  int curb = batch[n0];
  for (int n = n0; n < n1; ++n) {
    int b = batch[n];
    if (b != curb) {
      atomicAdd(&psum[curb * HC + c], acc);
      acc = 0.f;
      curb = b;
    }
    acc += (float)h16[(size_t)n * HC + c];
  }
  atomicAdd(&psum[curb * HC + c], acc);
}

// ---------------- classifier + log_softmax ----------------
__global__ __launch_bounds__(1024) void k_classify(const float* __restrict__ psum,
                                                   const int* __restrict__ batch,
                                                   const float* __restrict__ wlin,
                                                   const float* __restrict__ blin,
                                                   float* __restrict__ out) {
  int tid = threadIdx.x;
  int b = tid >> 4, o = tid & 15;
  int lo = 0, hi = N_NODES;
  while (lo < hi) { int mid = (lo + hi) >> 1; if (batch[mid] < b) lo = mid + 1; else hi = mid; }
  int start = lo;
  lo = 0; hi = N_NODES;
  while (lo < hi) { int mid = (lo + hi) >> 1; if (batch[mid] <= b) lo = mid + 1; else hi = mid; }
  float cnt = fmaxf((float)(lo - start), 1.0f);
  float dot = 0.f;
  for (int d = 0; d < HC; ++d) dot = fmaf(psum[b * HC + d], wlin[d * OUT_C + o], dot);
  float acc = dot / cnt + blin[o];
  float mx = acc;
#pragma unroll
  for (int off = 8; off > 0; off >>= 1) mx = fmaxf(mx, __shfl_xor(mx, off, 64));
  float ex = __expf(acc - mx);
  float sum = ex;
#pragma unroll
  for (int off = 8; off > 0; off >>= 1) sum += __shfl_xor(sum, off, 64);
  out[tid] = acc - mx - logf(sum);
}

extern "C" void kernel_launch(void* const* d_in, const int* in_sizes, int n_in,
                              void* d_out, int out_size, void* d_ws, size_t ws_size,
                              hipStream_t stream) {
  const float* x = (const float*)d_in[0];
  const int* ei = (const int*)d_in[1];
  const float* ea = (const float*)d_in[2];
  const int* batch = (const int*)d_in[3];
  const float* wq1 = (const float*)d_in[4];  const float* bq1 = (const float*)d_in[5];
  const float* wk1 = (const float*)d_in[6];  const float* bk1 = (const float*)d_in[7];
  const float* wv1 = (const float*)d_in[8];  const float* bv1 = (const float*)d_in[9];
  const float* we1 = (const float*)d_in[10];
  const float* ws1 = (const float*)d_in[11]; const float* bs1 = (const float*)d_in[12];
  const float* wq2 = (const float*)d_in[13]; const float* bq2 = (const float*)d_in[14];
  const float* wk2 = (const float*)d_in[15]; const float* bk2 = (const float*)d_in[16];
  const float* wv2 = (const float*)d_in[17]; const float* bv2 = (const float*)d_in[18];
  const float* we2 = (const float*)d_in[19];
  const float* ws2 = (const float*)d_in[20]; const float* bs2 = (const float*)d_in[21];
  const float* wlin = (const float*)d_in[22]; const float* blin = (const float*)d_in[23];

  const int* srcI = ei;
  const int* tgtI = ei + N_EDGES;

  char* wsb = (char*)d_ws;
  size_t off = 0;
  auto alloc = [&](size_t bytes) -> void* {
    void* ptr = wsb + off;
    off += (bytes + 255) & ~(size_t)255;
    return ptr;
  };
  __half* qn16 = (__half*)alloc((size_t)N_NODES * HC * 2);
  _Float16* kv16 = (_Float16*)alloc((size_t)N_NODES * 256 * 2);  // interleaved k|v
  __half* p16  = (__half*)alloc((size_t)N_NODES * HC * 2);
  _Float16* sk16 = (_Float16*)alloc((size_t)N_NODES * HC * 2);   // fp16 skip
  _Float16* h16 = (_Float16*)alloc((size_t)N_NODES * HC * 2);    // layer-2 output
  _Float16* in16 = (_Float16*)alloc((size_t)N_NODES * HC * 2);   // x16, then h(1)16
  _Float16* wt1 = (_Float16*)alloc((size_t)640 * HC * 2);
  _Float16* wt2 = (_Float16*)alloc((size_t)640 * HC * 2);
  float* bp1 = (float*)alloc((size_t)HC * 4);
  float* bp2 = (float*)alloc((size_t)HC * 4);
  float* psum = (float*)alloc((size_t)NGRAPH * HC * 4);
  int* deg    = (int*)alloc((size_t)N_NODES * 4);
  int* offs   = (int*)alloc((size_t)(N_NODES + 1) * 4);
  int* cursor = (int*)alloc((size_t)N_NODES * 4);
  int* srcs   = (int*)alloc((size_t)N_EDGES * 4);
  _Float16* eac = (_Float16*)alloc((size_t)N_EDGES * HID * 2);

  // CSR build (scatter fused with edge_attr permute+fp16 convert)
  hipMemsetAsync(deg, 0, (size_t)N_NODES * 4, stream);
  k_hist<<<(N_EDGES + 255) / 256, 256, 0, stream>>>(tgtI, deg);
  k_scan<<<1, 1024, 0, stream>>>(deg, offs, cursor);
  k_scatter<<<N_EDGES / 32, 256, 0, stream>>>(srcI, tgtI, cursor, ea, srcs, eac);

  // Conversions + weight packing
  k_conv_x<<<(N_NODES * HC / 8 + 255) / 256, 256, 0, stream>>>(x, in16);
  k_conv_w<<<512, 128, 0, stream>>>(wq1, wk1, wv1, ws1, wt1);
  k_conv_w<<<512, 128, 0, stream>>>(wq2, wk2, wv2, ws2, wt2);
  k_fold_p<<<128, 128, 0, stream>>>(wq1, bq1, we1, wt1, bp1);
  k_fold_p<<<128, 128, 0, stream>>>(wq2, bq2, we2, wt2, bp2);

  dim3 gemm_grid((N_NODES + 127) / 128, 5);
  // Layer 1
  k_gemm<<<gemm_grid, 256, 0, stream>>>(in16, wt1, bq1, bk1, bv1, bs1, bp1,
                                        qn16, kv16, sk16, p16);
  k_edge_attn<<<N_NODES / TPB, 64 * TPB, 0, stream>>>(
      offs, srcs, eac, (const _Float16*)qn16, kv16, sk16,
      (const _Float16*)p16, we1, in16);
  // Layer 2
  k_gemm<<<gemm_grid, 256, 0, stream>>>(in16, wt2, bq2, bk2, bv2, bs2, bp2,
                                        qn16, kv16, sk16, p16);
  k_edge_attn<<<N_NODES / TPB, 64 * TPB, 0, stream>>>(
      offs, srcs, eac, (const _Float16*)qn16, kv16, sk16,
      (const _Float16*)p16, we2, h16);

  // Pool + classify
  hipMemsetAsync(psum, 0, (size_t)NGRAPH * HC * 4, stream);
  k_pool_sum<<<N_NODES / PNB, 128, 0, stream>>>(h16, batch, psum);
  k_classify<<<1, 1024, 0, stream>>>(psum, batch, wlin, blin, (float*)d_out);
}

// Round 17
// 619.656 us; speedup vs baseline: 1.1699x; 1.0689x over previous
//
#include <hip/hip_runtime.h>
#include <hip/hip_fp16.h>

#define N_NODES 50000
#define N_EDGES 800000
#define IN_C 128
#define HID 32
#define HC 128
#define OUT_C 16
#define NGRAPH 64
#define PNB 125  // nodes per block in pool
#define TPB 2    // targets (waves) per block in edge attn
#define NPB_SCAN 1024
#define NSCAN_BLKS ((N_NODES + NPB_SCAN - 1) / NPB_SCAN)  // 49

typedef __attribute__((ext_vector_type(8))) _Float16 half8;
typedef __attribute__((ext_vector_type(4))) _Float16 half4v;
typedef __attribute__((ext_vector_type(2))) _Float16 half2v;
typedef __attribute__((ext_vector_type(4))) float floatx4;

// ---------------- CSR build ----------------
__global__ void k_hist(const int* __restrict__ tgt, int* __restrict__ deg) {
  int i = blockIdx.x * blockDim.x + threadIdx.x;
  if (i < N_EDGES) atomicAdd(&deg[tgt[i]], 1);
}

// 3-pass parallel scan (replaces single-block k_scan, which serialized one CU).
// Pass 1: per-block (1024 nodes) sums.
__global__ __launch_bounds__(256) void k_scan1(const int* __restrict__ deg,
                                               int* __restrict__ bsum) {
  int i4 = blockIdx.x * 256 + threadIdx.x;
  int4 d = {0, 0, 0, 0};
  if (i4 * 4 < N_NODES) d = ((const int4*)deg)[i4];
  int s = d.x + d.y + d.z + d.w;
#pragma unroll
  for (int off = 1; off < 64; off <<= 1) s += __shfl_xor(s, off, 64);
  __shared__ int ws[4];
  int lane = threadIdx.x & 63, w = threadIdx.x >> 6;
  if (lane == 0) ws[w] = s;
  __syncthreads();
  if (threadIdx.x == 0) bsum[blockIdx.x] = ws[0] + ws[1] + ws[2] + ws[3];
}

// Pass 2: exclusive scan of the 49 block sums (one wave).
__global__ void k_scan2(int* __restrict__ bsum) {
  int lane = threadIdx.x;
  int v = (lane < NSCAN_BLKS) ? bsum[lane] : 0;
  int x = v;
#pragma unroll
  for (int off = 1; off < 64; off <<= 1) {
    int t = __shfl_up(x, off, 64);
    if (lane >= off) x += t;
  }
  if (lane < NSCAN_BLKS) bsum[lane] = x - v;  // exclusive base
}

// Pass 3: per-block scan + base; writes offs[i+1..] and cursor[i..].
__global__ __launch_bounds__(256) void k_scan3(const int* __restrict__ deg,
                                               const int* __restrict__ bbase,
                                               int* __restrict__ offs,
                                               int* __restrict__ cursor) {
  int t = threadIdx.x, lane = t & 63, w = t >> 6;
  int i4 = blockIdx.x * 256 + t;
  int4 d = {0, 0, 0, 0};
  bool valid = (i4 * 4 < N_NODES);
  if (valid) d = ((const int4*)deg)[i4];
  int s0 = d.x, s1 = s0 + d.y, s2 = s1 + d.z, s3 = s2 + d.w;
  int x = s3;
#pragma unroll
  for (int off = 1; off < 64; off <<= 1) {
    int tt = __shfl_up(x, off, 64);
    if (lane >= off) x += tt;
  }
  __shared__ int ws[4];
  if (lane == 63) ws[w] = x;
  __syncthreads();
  int wadd = 0;
  for (int k = 0; k < w; ++k) wadd += ws[k];
  int base = bbase[blockIdx.x] + wadd + (x - s3);  // exclusive prefix of node i
  if (valid) {
    int i = i4 * 4;
    int4 cur = {base, base + s0, base + s1, base + s2};
    ((int4*)&cursor[i])[0] = cur;
    offs[i + 1] = base + s0;
    offs[i + 2] = base + s1;
    offs[i + 3] = base + s2;
    offs[i + 4] = base + s3;
  }
  if (blockIdx.x == 0 && t == 0) offs[0] = 0;
}

// Fused scatter: build srcs[] AND permute edge_attr into CSR order as fp16.
// 8 lanes per edge; leader does the atomic, pos broadcast via shfl; the 8
// lanes then move the 32-float row as coalesced 16B reads / 128B-line writes.
__global__ __launch_bounds__(256) void k_scatter(
    const int* __restrict__ src, const int* __restrict__ tgt,
    int* __restrict__ cursor, const float* __restrict__ ea,
    int* __restrict__ srcs, _Float16* __restrict__ eac) {
  int i = blockIdx.x * 32 + (threadIdx.x >> 3);
  int c = threadIdx.x & 7;
  int lane = threadIdx.x & 63;
  int pos = 0;
  if (c == 0) pos = atomicAdd(&cursor[tgt[i]], 1);
  pos = __shfl(pos, lane & 0x38, 64);   // broadcast from group leader
  if (c == 0) srcs[pos] = src[i];
  float4 v = *(const float4*)&ea[(size_t)i * HID + c * 4];
  half4v h = {(_Float16)v.x, (_Float16)v.y, (_Float16)v.z, (_Float16)v.w};
  *(half4v*)&eac[(size_t)pos * HID + c * 4] = h;
}

// ---------------- conversions ----------------
__global__ void k_conv_x(const float* __restrict__ x, _Float16* __restrict__ x16) {
  int i = blockIdx.x * 256 + threadIdx.x;
  if (i * 8 < N_NODES * HC) {
    float4 v0 = *(const float4*)&x[i * 8];
    float4 v1 = *(const float4*)&x[i * 8 + 4];
    half8 h = {(_Float16)v0.x, (_Float16)v0.y, (_Float16)v0.z, (_Float16)v0.w,
               (_Float16)v1.x, (_Float16)v1.y, (_Float16)v1.z, (_Float16)v1.w};
    *(half8*)&x16[i * 8] = h;
  }
}

// W^T packed [640 cols][128 k] fp16. Cols 0..511 here; 512..639 via k_fold_p.
__global__ __launch_bounds__(128) void k_conv_w(
    const float* __restrict__ wq, const float* __restrict__ wk,
    const float* __restrict__ wv, const float* __restrict__ ws,
    _Float16* __restrict__ wt) {
  int g = blockIdx.x;          // 0..511 global output col
  int k = threadIdx.x;         // 0..127
  const float* w = (g < 128) ? wq : (g < 256) ? wk : (g < 384) ? wv : ws;
  int c = g & 127;
  wt[g * HC + k] = (_Float16)w[k * HC + c];
}

// Fold p = q @ we^T into the node GEMM: wt cols 512..639 = wq @ W2, bp = bq @ W2
__global__ __launch_bounds__(128) void k_fold_p(const float* __restrict__ wq,
                                                const float* __restrict__ bq,
                                                const float* __restrict__ we,
                                                _Float16* __restrict__ wt,
                                                float* __restrict__ bp) {
  int c = blockIdx.x;          // 0..127 p-column
  int k = threadIdx.x;         // 0..127 input dim
  int hb = (c >> 5) << 5, j = c & 31;
  float s = 0.f;
#pragma unroll
  for (int d = 0; d < 32; ++d)
    s = fmaf(wq[k * HC + hb + d], we[j * HC + hb + d], s);
  wt[(size_t)(512 + c) * HC + k] = (_Float16)s;
  if (k == 0) {
    float b = 0.f;
    for (int d = 0; d < 32; ++d) b = fmaf(bq[hb + d], we[j * HC + hb + d], b);
    bp[c] = b;
  }
}

// ---------------- MFMA node GEMM (LDS-staged B) ----------------
// k (cb=1) and v (cb=2) write into interleaved kv[N][256]: k at +0, v at +128.
// skip (cb=3) stored fp16.
__global__ __launch_bounds__(256) void k_gemm(
    const _Float16* __restrict__ ain,   // [N][128] fp16
    const _Float16* __restrict__ wt,    // [640][128] fp16 = W^T
    const float* __restrict__ bq, const float* __restrict__ bk,
    const float* __restrict__ bv, const float* __restrict__ bs,
    const float* __restrict__ bp,
    __half* __restrict__ qn16, _Float16* __restrict__ kv16,
    _Float16* __restrict__ sk16, __half* __restrict__ p16) {
  __shared__ _Float16 Bs[128][132];    // +4 halves pad: ds_read 2-way (free)
  int tid = threadIdx.x;
  int wv = tid >> 6, lane = tid & 63;
  int quad = lane >> 4, l16 = lane & 15;
  int cb = blockIdx.y;                  // 0=q 1=k 2=v 3=skip 4=p

#pragma unroll
  for (int i = 0; i < 8; ++i) {
    int chunk = i * 256 + tid;
    int col = chunk >> 4, kc16 = chunk & 15;
    half8 b = *(const half8*)&wt[(size_t)(cb * 128 + col) * HC + kc16 * 8];
    *(half8*)&Bs[col][kc16 * 8] = b;
  }

  int r0 = blockIdx.x * 128 + wv * 32;
  half8 A[2][4];
#pragma unroll
  for (int m = 0; m < 2; ++m) {
    int arow = min(r0 + m * 16 + l16, N_NODES - 1);
#pragma unroll
    for (int kc = 0; kc < 4; ++kc)
      A[m][kc] = *(const half8*)&ain[(size_t)arow * HC + kc * 32 + quad * 8];
  }
  floatx4 acc[8][2];
#pragma unroll
  for (int ct = 0; ct < 8; ++ct) {
    acc[ct][0] = (floatx4){0.f, 0.f, 0.f, 0.f};
    acc[ct][1] = (floatx4){0.f, 0.f, 0.f, 0.f};
  }
  __syncthreads();

#pragma unroll
  for (int ct = 0; ct < 8; ++ct) {
#pragma unroll
    for (int kc = 0; kc < 4; ++kc) {
      half8 B = *(const half8*)&Bs[ct * 16 + l16][kc * 32 + quad * 8];
      acc[ct][0] = __builtin_amdgcn_mfma_f32_16x16x32_f16(A[0][kc], B, acc[ct][0], 0, 0, 0);
      acc[ct][1] = __builtin_amdgcn_mfma_f32_16x16x32_f16(A[1][kc], B, acc[ct][1], 0, 0, 0);
    }
  }

  const float* bias = (cb == 0) ? bq : (cb == 1) ? bk : (cb == 2) ? bv
                    : (cb == 3) ? bs : bp;
#pragma unroll
  for (int ct = 0; ct < 8; ++ct) {
    int lc = (ct << 4) + l16;
    float b = bias[lc];
#pragma unroll
    for (int m = 0; m < 2; ++m) {
#pragma unroll
      for (int reg = 0; reg < 4; ++reg) {
        int row = r0 + m * 16 + quad * 4 + reg;  // C/D: col=lane&15, row=quad*4+reg
        if (row < N_NODES) {
          float val = acc[ct][m][reg] + b;
          if (cb == 0) qn16[(size_t)row * HC + lc] = __float2half(val);
          else if (cb == 1) kv16[(size_t)row * 256 + lc] = (_Float16)val;
          else if (cb == 2) kv16[(size_t)row * 256 + 128 + lc] = (_Float16)val;
          else if (cb == 3) sk16[(size_t)row * HC + lc] = (_Float16)val;
          else p16[(size_t)row * HC + lc] = __float2half(val);
        }
      }
    }
  }
}

// ---------------- edge attention ----------------
// One wave per target. Per 16-edge chunk: batch-gather K/V/E to registers
// (12 independent loads = one latency exposure), compute from registers.
// fp16 skip input; writes ONLY fp16 output (pool reads fp16).
__device__ __forceinline__ float dot8(half8 a, half8 b, float c) {
#if __has_builtin(__builtin_amdgcn_fdot2)
#pragma unroll
  for (int i = 0; i < 4; ++i) {
    half2v x = {a[2 * i], a[2 * i + 1]};
    half2v y = {b[2 * i], b[2 * i + 1]};
    c = __builtin_amdgcn_fdot2(x, y, c, false);
  }
#else
#pragma unroll
  for (int i = 0; i < 8; ++i) c = fmaf((float)a[i], (float)b[i], c);
#endif
  return c;
}

// sum over the 4 lanes of a quad via DPP quad_perm (xor1 then xor2)
__device__ __forceinline__ float quad_red(float x) {
  int b = __builtin_amdgcn_update_dpp(0, __float_as_int(x), 0xB1, 0xF, 0xF, true);
  float y = x + __int_as_float(b);
  int c2 = __builtin_amdgcn_update_dpp(0, __float_as_int(y), 0x4E, 0xF, 0xF, true);
  return y + __int_as_float(c2);
}

__global__ __launch_bounds__(128) void k_edge_attn(
    const int* __restrict__ offs, const int* __restrict__ srcs,
    const _Float16* __restrict__ eac,
    const _Float16* __restrict__ qn, const _Float16* __restrict__ kv,
    const _Float16* __restrict__ sk,
    const _Float16* __restrict__ pn, const float* __restrict__ we,
    _Float16* __restrict__ o16) {
  int lane = threadIdx.x & 63;
  int wv_ = threadIdx.x >> 6;
  int t = blockIdx.x * TPB + wv_;
  int g = lane >> 4;          // edge subgroup 0..3
  int p = lane & 15;          // position within group
  int f0 = p << 3;            // feature base (8 feats, head = p>>2)
  int jd0 = (p & 3) << 3;     // ea-dim base (8 of 32 dims)

  half8 qh = *(const half8*)&qn[(size_t)t * HC + f0];
  half8 ph = *(const half8*)&pn[(size_t)t * HC + ((p >> 2) << 5) + jd0];

  int e0 = offs[t], e1 = offs[t + 1];
  const float inv_sqrt = 0.17677669529663687f;
  float den = 0.f;
  float acc[8], tac[8];
#pragma unroll
  for (int i = 0; i < 8; ++i) { acc[i] = 0.f; tac[i] = 0.f; }

  int sl = (e0 < e1) ? srcs[min(e0 + (lane & 15), e1 - 1)] : 0;
  for (int base = e0; base < e1; base += 16) {
    int cnt = e1 - base;               // remaining edges (>0)
    // ---- gather phase: 12 independent loads, all in flight at once ----
    half8 K[4], V[4], E[4];
#pragma unroll
    for (int i = 0; i < 4; ++i) {
      int j = 4 * g + i;
      int jc = min(j, cnt - 1);
      int s = __shfl(sl, jc, 64);
      const _Float16* kvp = &kv[(size_t)s * 256];
      K[i] = *(const half8*)&kvp[f0];
      V[i] = *(const half8*)&kvp[128 + f0];
      E[i] = *(const half8*)&eac[(size_t)(base + jc) * HID + jd0];
    }
    // issue next chunk's srcs load under the compute phase
    int nb = base + 16;
    int sl_n = (nb < e1) ? srcs[min(nb + (lane & 15), e1 - 1)] : 0;
    // ---- compute phase: 4 edges from registers ----
#pragma unroll
    for (int i = 0; i < 4; ++i) {
      int j = 4 * g + i;
      float part = dot8(qh, K[i], 0.f);
      part = dot8(ph, E[i], part);
      part = quad_red(part);           // full 32-dim dot for this head
      float w = (j < cnt) ? __expf(part * inv_sqrt) : 0.f;
      den += w;
#pragma unroll
      for (int q2 = 0; q2 < 8; ++q2) {
        acc[q2] = fmaf(w, (float)V[i][q2], acc[q2]);
        tac[q2] = fmaf(w, (float)E[i][q2], tac[q2]);
      }
    }
    sl = sl_n;
  }

  // merge the 4 edge-subgroups
#pragma unroll
  for (int i = 0; i < 8; ++i) {
    acc[i] += __shfl_xor(acc[i], 16, 64); acc[i] += __shfl_xor(acc[i], 32, 64);
    tac[i] += __shfl_xor(tac[i], 16, 64); tac[i] += __shfl_xor(tac[i], 32, 64);
  }
  den += __shfl_xor(den, 16, 64);
  den += __shfl_xor(den, 32, 64);

  // fx[f] = sum_j tac_h[j] * we[j][f]; j-range split across the 4 groups
  __shared__ float tl[TPB][16][9];
  if (g == 0) {
#pragma unroll
    for (int i = 0; i < 8; ++i) tl[wv_][p][i] = tac[i];
  }
  float fx[8];
#pragma unroll
  for (int i = 0; i < 8; ++i) fx[i] = 0.f;
  int r = (p & 12) + g;       // LDS row holding this head's j-range for group g
#pragma unroll
  for (int u = 0; u < 8; ++u) {
    float tv = tl[wv_][r][u];
    int j = (g << 3) + u;
    const float4* wr = (const float4*)&we[j * HC + f0];
    float4 w0 = wr[0], w1 = wr[1];
    fx[0] = fmaf(tv, w0.x, fx[0]); fx[1] = fmaf(tv, w0.y, fx[1]);
    fx[2] = fmaf(tv, w0.z, fx[2]); fx[3] = fmaf(tv, w0.w, fx[3]);
    fx[4] = fmaf(tv, w1.x, fx[4]); fx[5] = fmaf(tv, w1.y, fx[5]);
    fx[6] = fmaf(tv, w1.z, fx[6]); fx[7] = fmaf(tv, w1.w, fx[7]);
  }
#pragma unroll
  for (int i = 0; i < 8; ++i) {
    fx[i] += __shfl_xor(fx[i], 16, 64);
    fx[i] += __shfl_xor(fx[i], 32, 64);
  }

  if (g == 0) {
    float rd = (e1 > e0) ? (1.0f / den) : 0.f;
    half8 s8 = *(const half8*)&sk[(size_t)t * HC + f0];
    float o[8];
#pragma unroll
    for (int i = 0; i < 8; ++i) {
      o[i] = fmaf(acc[i] + fx[i], rd, (float)s8[i]);
      o[i] = o[i] > 0.f ? o[i] : __expf(o[i]) - 1.f;
    }
    half8 v16 = {(_Float16)o[0], (_Float16)o[1], (_Float16)o[2], (_Float16)o[3],
                 (_Float16)o[4], (_Float16)o[5], (_Float16)o[6], (_Float16)o[7]};
    *(half8*)&o16[(size_t)t * HC + f0] = v16;
  }
}

// ---------------- global mean pool (reads fp16 h) ----------------
__global__ __launch_bounds__(128) void k_pool_sum(const _Float16* __restrict__ h16,
                                                  const int* __restrict__ batch,
                                                  float* __restrict__ psum) {
  int c = threadIdx.x;
  int n0 = blockIdx.x * PNB;
  int n1 = n0 + PNB;
  float acc = 0.f;
  int curb = batch[n0];
  for (int n = n0; n < n1; ++n) {
    int b = batch[n];
    if (b != curb) {
      atomicAdd(&psum[curb * HC + c], acc);
      acc = 0.f;
      curb = b;
    }
    acc += (float)h16[(size_t)n * HC + c];
  }
  atomicAdd(&psum[curb * HC + c], acc);
}

// ---------------- classifier + log_softmax ----------------
__global__ __launch_bounds__(1024) void k_classify(const float* __restrict__ psum,
                                                   const int* __restrict__ batch,
                                                   const float* __restrict__ wlin,
                                                   const float* __restrict__ blin,
                                                   float* __restrict__ out) {
  int tid = threadIdx.x;
  int b = tid >> 4, o = tid & 15;
  int lo = 0, hi = N_NODES;
  while (lo < hi) { int mid = (lo + hi) >> 1; if (batch[mid] < b) lo = mid + 1; else hi = mid; }
  int start = lo;
  lo = 0; hi = N_NODES;
  while (lo < hi) { int mid = (lo + hi) >> 1; if (batch[mid] <= b) lo = mid + 1; else hi = mid; }
  float cnt = fmaxf((float)(lo - start), 1.0f);
  float dot = 0.f;
  for (int d = 0; d < HC; ++d) dot = fmaf(psum[b * HC + d], wlin[d * OUT_C + o], dot);
  float acc = dot / cnt + blin[o];
  float mx = acc;
#pragma unroll
  for (int off = 8; off > 0; off >>= 1) mx = fmaxf(mx, __shfl_xor(mx, off, 64));
  float ex = __expf(acc - mx);
  float sum = ex;
#pragma unroll
  for (int off = 8; off > 0; off >>= 1) sum += __shfl_xor(sum, off, 64);
  out[tid] = acc - mx - logf(sum);
}

extern "C" void kernel_launch(void* const* d_in, const int* in_sizes, int n_in,
                              void* d_out, int out_size, void* d_ws, size_t ws_size,
                              hipStream_t stream) {
  const float* x = (const float*)d_in[0];
  const int* ei = (const int*)d_in[1];
  const float* ea = (const float*)d_in[2];
  const int* batch = (const int*)d_in[3];
  const float* wq1 = (const float*)d_in[4];  const float* bq1 = (const float*)d_in[5];
  const float* wk1 = (const float*)d_in[6];  const float* bk1 = (const float*)d_in[7];
  const float* wv1 = (const float*)d_in[8];  const float* bv1 = (const float*)d_in[9];
  const float* we1 = (const float*)d_in[10];
  const float* ws1 = (const float*)d_in[11]; const float* bs1 = (const float*)d_in[12];
  const float* wq2 = (const float*)d_in[13]; const float* bq2 = (const float*)d_in[14];
  const float* wk2 = (const float*)d_in[15]; const float* bk2 = (const float*)d_in[16];
  const float* wv2 = (const float*)d_in[17]; const float* bv2 = (const float*)d_in[18];
  const float* we2 = (const float*)d_in[19];
  const float* ws2 = (const float*)d_in[20]; const float* bs2 = (const float*)d_in[21];
  const float* wlin = (const float*)d_in[22]; const float* blin = (const float*)d_in[23];

  const int* srcI = ei;
  const int* tgtI = ei + N_EDGES;

  char* wsb = (char*)d_ws;
  size_t off = 0;
  auto alloc = [&](size_t bytes) -> void* {
    void* ptr = wsb + off;
    off += (bytes + 255) & ~(size_t)255;
    return ptr;
  };
  __half* qn16 = (__half*)alloc((size_t)N_NODES * HC * 2);
  _Float16* kv16 = (_Float16*)alloc((size_t)N_NODES * 256 * 2);  // interleaved k|v
  __half* p16  = (__half*)alloc((size_t)N_NODES * HC * 2);
  _Float16* sk16 = (_Float16*)alloc((size_t)N_NODES * HC * 2);   // fp16 skip
  _Float16* h16 = (_Float16*)alloc((size_t)N_NODES * HC * 2);    // layer-2 output
  _Float16* in16 = (_Float16*)alloc((size_t)N_NODES * HC * 2);   // x16, then h(1)16
  _Float16* wt1 = (_Float16*)alloc((size_t)640 * HC * 2);
  _Float16* wt2 = (_Float16*)alloc((size_t)640 * HC * 2);
  float* bp1 = (float*)alloc((size_t)HC * 4);
  float* bp2 = (float*)alloc((size_t)HC * 4);
  float* psum = (float*)alloc((size_t)NGRAPH * HC * 4);
  int* deg    = (int*)alloc((size_t)N_NODES * 4);
  int* offs   = (int*)alloc((size_t)(N_NODES + 1) * 4);
  int* cursor = (int*)alloc((size_t)N_NODES * 4);
  int* srcs   = (int*)alloc((size_t)N_EDGES * 4);
  int* bsum   = (int*)alloc((size_t)NSCAN_BLKS * 4);
  _Float16* eac = (_Float16*)alloc((size_t)N_EDGES * HID * 2);

  // CSR build (parallel 3-pass scan; scatter fused with edge_attr permute)
  hipMemsetAsync(deg, 0, (size_t)N_NODES * 4, stream);
  k_hist<<<(N_EDGES + 255) / 256, 256, 0, stream>>>(tgtI, deg);
  k_scan1<<<NSCAN_BLKS, 256, 0, stream>>>(deg, bsum);
  k_scan2<<<1, 64, 0, stream>>>(bsum);
  k_scan3<<<NSCAN_BLKS, 256, 0, stream>>>(deg, bsum, offs, cursor);
  k_scatter<<<N_EDGES / 32, 256, 0, stream>>>(srcI, tgtI, cursor, ea, srcs, eac);

  // Conversions + weight packing
  k_conv_x<<<(N_NODES * HC / 8 + 255) / 256, 256, 0, stream>>>(x, in16);
  k_conv_w<<<512, 128, 0, stream>>>(wq1, wk1, wv1, ws1, wt1);
  k_conv_w<<<512, 128, 0, stream>>>(wq2, wk2, wv2, ws2, wt2);
  k_fold_p<<<128, 128, 0, stream>>>(wq1, bq1, we1, wt1, bp1);
  k_fold_p<<<128, 128, 0, stream>>>(wq2, bq2, we2, wt2, bp2);

  dim3 gemm_grid((N_NODES + 127) / 128, 5);
  // Layer 1
  k_gemm<<<gemm_grid, 256, 0, stream>>>(in16, wt1, bq1, bk1, bv1, bs1, bp1,
                                        qn16, kv16, sk16, p16);
  k_edge_attn<<<N_NODES / TPB, 64 * TPB, 0, stream>>>(
      offs, srcs, eac, (const _Float16*)qn16, kv16, sk16,
      (const _Float16*)p16, we1, in16);
  // Layer 2
  k_gemm<<<gemm_grid, 256, 0, stream>>>(in16, wt2, bq2, bk2, bv2, bs2, bp2,
                                        qn16, kv16, sk16, p16);
  k_edge_attn<<<N_NODES / TPB, 64 * TPB, 0, stream>>>(
      offs, srcs, eac, (const _Float16*)qn16, kv16, sk16,
      (const _Float16*)p16, we2, h16);

  // Pool + classify
  hipMemsetAsync(psum, 0, (size_t)NGRAPH * HC * 4, stream);
  k_pool_sum<<<N_NODES / PNB, 128, 0, stream>>>(h16, batch, psum);
  k_classify<<<1, 1024, 0, stream>>>(psum, batch, wlin, blin, (float*)d_out);
}

// Round 18
// 619.303 us; speedup vs baseline: 1.1705x; 1.0006x over previous
//
#include <hip/hip_runtime.h>
#include <hip/hip_fp16.h>

#define N_NODES 50000
#define N_EDGES 800000
#define IN_C 128
#define HID 32
#define HC 128
#define OUT_C 16
#define NGRAPH 64
#define PNB 125  // nodes per block in pool
#define TPB 2    // targets (waves) per block in edge attn
#define NPB_SCAN 1024
#define NSCAN_BLKS ((N_NODES + NPB_SCAN - 1) / NPB_SCAN)  // 49

typedef __attribute__((ext_vector_type(8))) _Float16 half8;
typedef __attribute__((ext_vector_type(4))) _Float16 half4v;
typedef __attribute__((ext_vector_type(2))) _Float16 half2v;
typedef __attribute__((ext_vector_type(4))) float floatx4;

// ---------------- CSR build ----------------
__global__ void k_hist(const int* __restrict__ tgt, int* __restrict__ deg) {
  int i = blockIdx.x * blockDim.x + threadIdx.x;
  if (i < N_EDGES) atomicAdd(&deg[tgt[i]], 1);
}

// 3-pass parallel scan. Pass 1: per-block (1024 nodes) sums.
__global__ __launch_bounds__(256) void k_scan1(const int* __restrict__ deg,
                                               int* __restrict__ bsum) {
  int i4 = blockIdx.x * 256 + threadIdx.x;
  int4 d = {0, 0, 0, 0};
  if (i4 * 4 < N_NODES) d = ((const int4*)deg)[i4];
  int s = d.x + d.y + d.z + d.w;
#pragma unroll
  for (int off = 1; off < 64; off <<= 1) s += __shfl_xor(s, off, 64);
  __shared__ int ws[4];
  int lane = threadIdx.x & 63, w = threadIdx.x >> 6;
  if (lane == 0) ws[w] = s;
  __syncthreads();
  if (threadIdx.x == 0) bsum[blockIdx.x] = ws[0] + ws[1] + ws[2] + ws[3];
}

// Pass 2: exclusive scan of the 49 block sums (one wave).
__global__ void k_scan2(int* __restrict__ bsum) {
  int lane = threadIdx.x;
  int v = (lane < NSCAN_BLKS) ? bsum[lane] : 0;
  int x = v;
#pragma unroll
  for (int off = 1; off < 64; off <<= 1) {
    int t = __shfl_up(x, off, 64);
    if (lane >= off) x += t;
  }
  if (lane < NSCAN_BLKS) bsum[lane] = x - v;  // exclusive base
}

// Pass 3: per-block scan + base; writes offs[i+1..] and cursor[i..].
__global__ __launch_bounds__(256) void k_scan3(const int* __restrict__ deg,
                                               const int* __restrict__ bbase,
                                               int* __restrict__ offs,
                                               int* __restrict__ cursor) {
  int t = threadIdx.x, lane = t & 63, w = t >> 6;
  int i4 = blockIdx.x * 256 + t;
  int4 d = {0, 0, 0, 0};
  bool valid = (i4 * 4 < N_NODES);
  if (valid) d = ((const int4*)deg)[i4];
  int s0 = d.x, s1 = s0 + d.y, s2 = s1 + d.z, s3 = s2 + d.w;
  int x = s3;
#pragma unroll
  for (int off = 1; off < 64; off <<= 1) {
    int tt = __shfl_up(x, off, 64);
    if (lane >= off) x += tt;
  }
  __shared__ int ws[4];
  if (lane == 63) ws[w] = x;
  __syncthreads();
  int wadd = 0;
  for (int k = 0; k < w; ++k) wadd += ws[k];
  int base = bbase[blockIdx.x] + wadd + (x - s3);  // exclusive prefix of node i
  if (valid) {
    int i = i4 * 4;
    int4 cur = {base, base + s0, base + s1, base + s2};
    ((int4*)&cursor[i])[0] = cur;
    offs[i + 1] = base + s0;
    offs[i + 2] = base + s1;
    offs[i + 3] = base + s2;
    offs[i + 4] = base + s3;
  }
  if (blockIdx.x == 0 && t == 0) offs[0] = 0;
}

// Fused scatter: build srcs[] AND permute edge_attr into CSR order as fp16.
__global__ __launch_bounds__(256) void k_scatter(
    const int* __restrict__ src, const int* __restrict__ tgt,
    int* __restrict__ cursor, const float* __restrict__ ea,
    int* __restrict__ srcs, _Float16* __restrict__ eac) {
  int i = blockIdx.x * 32 + (threadIdx.x >> 3);
  int c = threadIdx.x & 7;
  int lane = threadIdx.x & 63;
  int pos = 0;
  if (c == 0) pos = atomicAdd(&cursor[tgt[i]], 1);
  pos = __shfl(pos, lane & 0x38, 64);   // broadcast from group leader
  if (c == 0) srcs[pos] = src[i];
  float4 v = *(const float4*)&ea[(size_t)i * HID + c * 4];
  half4v h = {(_Float16)v.x, (_Float16)v.y, (_Float16)v.z, (_Float16)v.w};
  *(half4v*)&eac[(size_t)pos * HID + c * 4] = h;
}

// ---------------- weight prep (fused transpose + p-fold) ----------------
// wt cols 0..511 = [wq|wk|wv|ws]^T; cols 512..639 = (wq @ W2)^T; bp = bq @ W2
// where W2[f][c] = we[c&31][f] for same head (block-diagonal).
__global__ __launch_bounds__(128) void k_prep_w(
    const float* __restrict__ wq, const float* __restrict__ wk,
    const float* __restrict__ wv, const float* __restrict__ ws,
    const float* __restrict__ bq, const float* __restrict__ we,
    _Float16* __restrict__ wt, float* __restrict__ bp) {
  int g = blockIdx.x;          // 0..639 output col
  int k = threadIdx.x;         // 0..127 input dim
  if (g < 512) {
    const float* w = (g < 128) ? wq : (g < 256) ? wk : (g < 384) ? wv : ws;
    int c = g & 127;
    wt[(size_t)g * HC + k] = (_Float16)w[k * HC + c];
  } else {
    int c = g - 512;
    int hb = (c >> 5) << 5, j = c & 31;
    float s = 0.f;
#pragma unroll
    for (int d = 0; d < 32; ++d)
      s = fmaf(wq[k * HC + hb + d], we[j * HC + hb + d], s);
    wt[(size_t)g * HC + k] = (_Float16)s;
    if (k == 0) {
      float b = 0.f;
      for (int d = 0; d < 32; ++d) b = fmaf(bq[hb + d], we[j * HC + hb + d], b);
      bp[c] = b;
    }
  }
}

// ---------------- MFMA node GEMM (LDS-staged B) ----------------
// IN32: layer-1 reads fp32 x directly, converting in-register (same rounding
// as the old conv_x pass -> bit-identical). k/v interleaved kv[N][256].
template <bool IN32>
__global__ __launch_bounds__(256) void k_gemm(
    const void* __restrict__ ain_,      // [N][128] fp32 (IN32) or fp16
    const _Float16* __restrict__ wt,    // [640][128] fp16 = W^T
    const float* __restrict__ bq, const float* __restrict__ bk,
    const float* __restrict__ bv, const float* __restrict__ bs,
    const float* __restrict__ bp,
    __half* __restrict__ qn16, _Float16* __restrict__ kv16,
    _Float16* __restrict__ sk16, __half* __restrict__ p16) {
  __shared__ _Float16 Bs[128][132];    // +4 halves pad: ds_read 2-way (free)
  int tid = threadIdx.x;
  int wv = tid >> 6, lane = tid & 63;
  int quad = lane >> 4, l16 = lane & 15;
  int cb = blockIdx.y;                  // 0=q 1=k 2=v 3=skip 4=p

#pragma unroll
  for (int i = 0; i < 8; ++i) {
    int chunk = i * 256 + tid;
    int col = chunk >> 4, kc16 = chunk & 15;
    half8 b = *(const half8*)&wt[(size_t)(cb * 128 + col) * HC + kc16 * 8];
    *(half8*)&Bs[col][kc16 * 8] = b;
  }

  int r0 = blockIdx.x * 128 + wv * 32;
  half8 A[2][4];
#pragma unroll
  for (int m = 0; m < 2; ++m) {
    int arow = min(r0 + m * 16 + l16, N_NODES - 1);
#pragma unroll
    for (int kc = 0; kc < 4; ++kc) {
      if constexpr (IN32) {
        const float* ain = (const float*)ain_;
        const float4* ap = (const float4*)&ain[(size_t)arow * HC + kc * 32 + quad * 8];
        float4 a0 = ap[0], a1 = ap[1];
        A[m][kc] = (half8){(_Float16)a0.x, (_Float16)a0.y, (_Float16)a0.z,
                           (_Float16)a0.w, (_Float16)a1.x, (_Float16)a1.y,
                           (_Float16)a1.z, (_Float16)a1.w};
      } else {
        const _Float16* ain = (const _Float16*)ain_;
        A[m][kc] = *(const half8*)&ain[(size_t)arow * HC + kc * 32 + quad * 8];
      }
    }
  }
  floatx4 acc[8][2];
#pragma unroll
  for (int ct = 0; ct < 8; ++ct) {
    acc[ct][0] = (floatx4){0.f, 0.f, 0.f, 0.f};
    acc[ct][1] = (floatx4){0.f, 0.f, 0.f, 0.f};
  }
  __syncthreads();

#pragma unroll
  for (int ct = 0; ct < 8; ++ct) {
#pragma unroll
    for (int kc = 0; kc < 4; ++kc) {
      half8 B = *(const half8*)&Bs[ct * 16 + l16][kc * 32 + quad * 8];
      acc[ct][0] = __builtin_amdgcn_mfma_f32_16x16x32_f16(A[0][kc], B, acc[ct][0], 0, 0, 0);
      acc[ct][1] = __builtin_amdgcn_mfma_f32_16x16x32_f16(A[1][kc], B, acc[ct][1], 0, 0, 0);
    }
  }

  const float* bias = (cb == 0) ? bq : (cb == 1) ? bk : (cb == 2) ? bv
                    : (cb == 3) ? bs : bp;
#pragma unroll
  for (int ct = 0; ct < 8; ++ct) {
    int lc = (ct << 4) + l16;
    float b = bias[lc];
#pragma unroll
    for (int m = 0; m < 2; ++m) {
#pragma unroll
      for (int reg = 0; reg < 4; ++reg) {
        int row = r0 + m * 16 + quad * 4 + reg;  // C/D: col=lane&15, row=quad*4+reg
        if (row < N_NODES) {
          float val = acc[ct][m][reg] + b;
          if (cb == 0) qn16[(size_t)row * HC + lc] = __float2half(val);
          else if (cb == 1) kv16[(size_t)row * 256 + lc] = (_Float16)val;
          else if (cb == 2) kv16[(size_t)row * 256 + 128 + lc] = (_Float16)val;
          else if (cb == 3) sk16[(size_t)row * HC + lc] = (_Float16)val;
          else p16[(size_t)row * HC + lc] = __float2half(val);
        }
      }
    }
  }
}

// ---------------- edge attention ----------------
// One wave per target. Per 16-edge chunk: batch-gather K/V/E to registers
// (12 independent loads = one latency exposure), compute from registers.
__device__ __forceinline__ float dot8(half8 a, half8 b, float c) {
#if __has_builtin(__builtin_amdgcn_fdot2)
#pragma unroll
  for (int i = 0; i < 4; ++i) {
    half2v x = {a[2 * i], a[2 * i + 1]};
    half2v y = {b[2 * i], b[2 * i + 1]};
    c = __builtin_amdgcn_fdot2(x, y, c, false);
  }
#else
#pragma unroll
  for (int i = 0; i < 8; ++i) c = fmaf((float)a[i], (float)b[i], c);
#endif
  return c;
}

// sum over the 4 lanes of a quad via DPP quad_perm (xor1 then xor2)
__device__ __forceinline__ float quad_red(float x) {
  int b = __builtin_amdgcn_update_dpp(0, __float_as_int(x), 0xB1, 0xF, 0xF, true);
  float y = x + __int_as_float(b);
  int c2 = __builtin_amdgcn_update_dpp(0, __float_as_int(y), 0x4E, 0xF, 0xF, true);
  return y + __int_as_float(c2);
}

__global__ __launch_bounds__(128) void k_edge_attn(
    const int* __restrict__ offs, const int* __restrict__ srcs,
    const _Float16* __restrict__ eac,
    const _Float16* __restrict__ qn, const _Float16* __restrict__ kv,
    const _Float16* __restrict__ sk,
    const _Float16* __restrict__ pn, const float* __restrict__ we,
    _Float16* __restrict__ o16) {
  int lane = threadIdx.x & 63;
  int wv_ = threadIdx.x >> 6;
  int t = blockIdx.x * TPB + wv_;
  int g = lane >> 4;          // edge subgroup 0..3
  int p = lane & 15;          // position within group
  int f0 = p << 3;            // feature base (8 feats, head = p>>2)
  int jd0 = (p & 3) << 3;     // ea-dim base (8 of 32 dims)

  half8 qh = *(const half8*)&qn[(size_t)t * HC + f0];
  half8 ph = *(const half8*)&pn[(size_t)t * HC + ((p >> 2) << 5) + jd0];

  int e0 = offs[t], e1 = offs[t + 1];
  const float inv_sqrt = 0.17677669529663687f;
  float den = 0.f;
  float acc[8], tac[8];
#pragma unroll
  for (int i = 0; i < 8; ++i) { acc[i] = 0.f; tac[i] = 0.f; }

  int sl = (e0 < e1) ? srcs[min(e0 + (lane & 15), e1 - 1)] : 0;
  for (int base = e0; base < e1; base += 16) {
    int cnt = e1 - base;               // remaining edges (>0)
    // ---- gather phase: 12 independent loads, all in flight at once ----
    half8 K[4], V[4], E[4];
#pragma unroll
    for (int i = 0; i < 4; ++i) {
      int j = 4 * g + i;
      int jc = min(j, cnt - 1);
      int s = __shfl(sl, jc, 64);
      const _Float16* kvp = &kv[(size_t)s * 256];
      K[i] = *(const half8*)&kvp[f0];
      V[i] = *(const half8*)&kvp[128 + f0];
      E[i] = *(const half8*)&eac[(size_t)(base + jc) * HID + jd0];
    }
    // issue next chunk's srcs load under the compute phase
    int nb = base + 16;
    int sl_n = (nb < e1) ? srcs[min(nb + (lane & 15), e1 - 1)] : 0;
    // ---- compute phase: 4 edges from registers ----
#pragma unroll
    for (int i = 0; i < 4; ++i) {
      int j = 4 * g + i;
      float part = dot8(qh, K[i], 0.f);
      part = dot8(ph, E[i], part);
      part = quad_red(part);           // full 32-dim dot for this head
      float w = (j < cnt) ? __expf(part * inv_sqrt) : 0.f;
      den += w;
#pragma unroll
      for (int q2 = 0; q2 < 8; ++q2) {
        acc[q2] = fmaf(w, (float)V[i][q2], acc[q2]);
        tac[q2] = fmaf(w, (float)E[i][q2], tac[q2]);
      }
    }
    sl = sl_n;
  }

  // merge the 4 edge-subgroups
#pragma unroll
  for (int i = 0; i < 8; ++i) {
    acc[i] += __shfl_xor(acc[i], 16, 64); acc[i] += __shfl_xor(acc[i], 32, 64);
    tac[i] += __shfl_xor(tac[i], 16, 64); tac[i] += __shfl_xor(tac[i], 32, 64);
  }
  den += __shfl_xor(den, 16, 64);
  den += __shfl_xor(den, 32, 64);

  // fx[f] = sum_j tac_h[j] * we[j][f]; j-range split across the 4 groups
  __shared__ float tl[TPB][16][9];
  if (g == 0) {
#pragma unroll
    for (int i = 0; i < 8; ++i) tl[wv_][p][i] = tac[i];
  }
  float fx[8];
#pragma unroll
  for (int i = 0; i < 8; ++i) fx[i] = 0.f;
  int r = (p & 12) + g;       // LDS row holding this head's j-range for group g
#pragma unroll
  for (int u = 0; u < 8; ++u) {
    float tv = tl[wv_][r][u];
    int j = (g << 3) + u;
    const float4* wr = (const float4*)&we[j * HC + f0];
    float4 w0 = wr[0], w1 = wr[1];
    fx[0] = fmaf(tv, w0.x, fx[0]); fx[1] = fmaf(tv, w0.y, fx[1]);
    fx[2] = fmaf(tv, w0.z, fx[2]); fx[3] = fmaf(tv, w0.w, fx[3]);
    fx[4] = fmaf(tv, w1.x, fx[4]); fx[5] = fmaf(tv, w1.y, fx[5]);
    fx[6] = fmaf(tv, w1.z, fx[6]); fx[7] = fmaf(tv, w1.w, fx[7]);
  }
#pragma unroll
  for (int i = 0; i < 8; ++i) {
    fx[i] += __shfl_xor(fx[i], 16, 64);
    fx[i] += __shfl_xor(fx[i], 32, 64);
  }

  if (g == 0) {
    float rd = (e1 > e0) ? (1.0f / den) : 0.f;
    half8 s8 = *(const half8*)&sk[(size_t)t * HC + f0];
    float o[8];
#pragma unroll
    for (int i = 0; i < 8; ++i) {
      o[i] = fmaf(acc[i] + fx[i], rd, (float)s8[i]);
      o[i] = o[i] > 0.f ? o[i] : __expf(o[i]) - 1.f;
    }
    half8 v16 = {(_Float16)o[0], (_Float16)o[1], (_Float16)o[2], (_Float16)o[3],
                 (_Float16)o[4], (_Float16)o[5], (_Float16)o[6], (_Float16)o[7]};
    *(half8*)&o16[(size_t)t * HC + f0] = v16;
  }
}

// ---------------- global mean pool (reads fp16 h) ----------------
__global__ __launch_bounds__(128) void k_pool_sum(const _Float16* __restrict__ h16,
                                                  const int* __restrict__ batch,
                                                  float* __restrict__ psum) {
  int c = threadIdx.x;
  int n0 = blockIdx.x * PNB;
  int n1 = n0 + PNB;
  float acc = 0.f;
  int curb = batch[n0];
  for (int n = n0; n < n1; ++n) {
    int b = batch[n];
    if (b != curb) {
      atomicAdd(&psum[curb * HC + c], acc);
      acc = 0.f;
      curb = b;
    }
    acc += (float)h16[(size_t)n * HC + c];
  }
  atomicAdd(&psum[curb * HC + c], acc);
}

// ---------------- classifier + log_softmax ----------------
__global__ __launch_bounds__(1024) void k_classify(const float* __restrict__ psum,
                                                   const int* __restrict__ batch,
                                                   const float* __restrict__ wlin,
                                                   const float* __restrict__ blin,
                                                   float* __restrict__ out) {
  int tid = threadIdx.x;
  int b = tid >> 4, o = tid & 15;
  int lo = 0, hi = N_NODES;
  while (lo < hi) { int mid = (lo + hi) >> 1; if (batch[mid] < b) lo = mid + 1; else hi = mid; }
  int start = lo;
  lo = 0; hi = N_NODES;
  while (lo < hi) { int mid = (lo + hi) >> 1; if (batch[mid] <= b) lo = mid + 1; else hi = mid; }
  float cnt = fmaxf((float)(lo - start), 1.0f);
  float dot = 0.f;
  for (int d = 0; d < HC; ++d) dot = fmaf(psum[b * HC + d], wlin[d * OUT_C + o], dot);
  float acc = dot / cnt + blin[o];
  float mx = acc;
#pragma unroll
  for (int off = 8; off > 0; off >>= 1) mx = fmaxf(mx, __shfl_xor(mx, off, 64));
  float ex = __expf(acc - mx);
  float sum = ex;
#pragma unroll
  for (int off = 8; off > 0; off >>= 1) sum += __shfl_xor(sum, off, 64);
  out[tid] = acc - mx - logf(sum);
}

extern "C" void kernel_launch(void* const* d_in, const int* in_sizes, int n_in,
                              void* d_out, int out_size, void* d_ws, size_t ws_size,
                              hipStream_t stream) {
  const float* x = (const float*)d_in[0];
  const int* ei = (const int*)d_in[1];
  const float* ea = (const float*)d_in[2];
  const int* batch = (const int*)d_in[3];
  const float* wq1 = (const float*)d_in[4];  const float* bq1 = (const float*)d_in[5];
  const float* wk1 = (const float*)d_in[6];  const float* bk1 = (const float*)d_in[7];
  const float* wv1 = (const float*)d_in[8];  const float* bv1 = (const float*)d_in[9];
  const float* we1 = (const float*)d_in[10];
  const float* ws1 = (const float*)d_in[11]; const float* bs1 = (const float*)d_in[12];
  const float* wq2 = (const float*)d_in[13]; const float* bq2 = (const float*)d_in[14];
  const float* wk2 = (const float*)d_in[15]; const float* bk2 = (const float*)d_in[16];
  const float* wv2 = (const float*)d_in[17]; const float* bv2 = (const float*)d_in[18];
  const float* we2 = (const float*)d_in[19];
  const float* ws2 = (const float*)d_in[20]; const float* bs2 = (const float*)d_in[21];
  const float* wlin = (const float*)d_in[22]; const float* blin = (const float*)d_in[23];

  const int* srcI = ei;
  const int* tgtI = ei + N_EDGES;

  char* wsb = (char*)d_ws;
  size_t off = 0;
  auto alloc = [&](size_t bytes) -> void* {
    void* ptr = wsb + off;
    off += (bytes + 255) & ~(size_t)255;
    return ptr;
  };
  __half* qn16 = (__half*)alloc((size_t)N_NODES * HC * 2);
  _Float16* kv16 = (_Float16*)alloc((size_t)N_NODES * 256 * 2);  // interleaved k|v
  __half* p16  = (__half*)alloc((size_t)N_NODES * HC * 2);
  _Float16* sk16 = (_Float16*)alloc((size_t)N_NODES * HC * 2);   // fp16 skip
  _Float16* h16 = (_Float16*)alloc((size_t)N_NODES * HC * 2);    // layer-2 output
  _Float16* in16 = (_Float16*)alloc((size_t)N_NODES * HC * 2);   // layer-1 output
  _Float16* wt1 = (_Float16*)alloc((size_t)640 * HC * 2);
  _Float16* wt2 = (_Float16*)alloc((size_t)640 * HC * 2);
  float* bp1 = (float*)alloc((size_t)HC * 4);
  float* bp2 = (float*)alloc((size_t)HC * 4);
  float* psum = (float*)alloc((size_t)NGRAPH * HC * 4);
  int* deg    = (int*)alloc((size_t)N_NODES * 4);
  int* offs   = (int*)alloc((size_t)(N_NODES + 1) * 4);
  int* cursor = (int*)alloc((size_t)N_NODES * 4);
  int* srcs   = (int*)alloc((size_t)N_EDGES * 4);
  int* bsum   = (int*)alloc((size_t)NSCAN_BLKS * 4);
  _Float16* eac = (_Float16*)alloc((size_t)N_EDGES * HID * 2);

  // CSR build (parallel 3-pass scan; scatter fused with edge_attr permute)
  hipMemsetAsync(deg, 0, (size_t)N_NODES * 4, stream);
  k_hist<<<(N_EDGES + 255) / 256, 256, 0, stream>>>(tgtI, deg);
  k_scan1<<<NSCAN_BLKS, 256, 0, stream>>>(deg, bsum);
  k_scan2<<<1, 64, 0, stream>>>(bsum);
  k_scan3<<<NSCAN_BLKS, 256, 0, stream>>>(deg, bsum, offs, cursor);
  k_scatter<<<N_EDGES / 32, 256, 0, stream>>>(srcI, tgtI, cursor, ea, srcs, eac);

  // Weight prep (fused transpose + p-fold), one dispatch per layer
  k_prep_w<<<640, 128, 0, stream>>>(wq1, wk1, wv1, ws1, bq1, we1, wt1, bp1);
  k_prep_w<<<640, 128, 0, stream>>>(wq2, wk2, wv2, ws2, bq2, we2, wt2, bp2);

  dim3 gemm_grid((N_NODES + 127) / 128, 5);
  // Layer 1 (reads fp32 x directly; in-register fp16 convert == old conv_x)
  k_gemm<true><<<gemm_grid, 256, 0, stream>>>(x, wt1, bq1, bk1, bv1, bs1, bp1,
                                              qn16, kv16, sk16, p16);
  k_edge_attn<<<N_NODES / TPB, 64 * TPB, 0, stream>>>(
      offs, srcs, eac, (const _Float16*)qn16, kv16, sk16,
      (const _Float16*)p16, we1, in16);
  // Layer 2
  k_gemm<false><<<gemm_grid, 256, 0, stream>>>(in16, wt2, bq2, bk2, bv2, bs2, bp2,
                                               qn16, kv16, sk16, p16);
  k_edge_attn<<<N_NODES / TPB, 64 * TPB, 0, stream>>>(
      offs, srcs, eac, (const _Float16*)qn16, kv16, sk16,
      (const _Float16*)p16, we2, h16);

  // Pool + classify
  hipMemsetAsync(psum, 0, (size_t)NGRAPH * HC * 4, stream);
  k_pool_sum<<<N_NODES / PNB, 128, 0, stream>>>(h16, batch, psum);
  k_classify<<<1, 1024, 0, stream>>>(psum, batch, wlin, blin, (float*)d_out);
}

// Round 19
// 564.729 us; speedup vs baseline: 1.2836x; 1.0966x over previous
//
#include <hip/hip_runtime.h>
#include <hip/hip_fp16.h>

#define N_NODES 50000
#define N_EDGES 800000
#define IN_C 128
#define HID 32
#define HC 128
#define OUT_C 16
#define NGRAPH 64
#define PNB 125  // nodes per block in pool
#define TPB 2    // targets (waves) per block in edge attn
#define NPB_SCAN 1024
#define NSCAN_BLKS ((N_NODES + NPB_SCAN - 1) / NPB_SCAN)  // 49

typedef __attribute__((ext_vector_type(8))) _Float16 half8;
typedef __attribute__((ext_vector_type(4))) _Float16 half4v;
typedef __attribute__((ext_vector_type(2))) _Float16 half2v;
typedef __attribute__((ext_vector_type(4))) float floatx4;

// ---------------- CSR build ----------------
__global__ void k_hist(const int* __restrict__ tgt, int* __restrict__ deg) {
  int i = blockIdx.x * blockDim.x + threadIdx.x;
  if (i < N_EDGES) atomicAdd(&deg[tgt[i]], 1);
}

// 3-pass parallel scan. Pass 1: per-block (1024 nodes) sums.
__global__ __launch_bounds__(256) void k_scan1(const int* __restrict__ deg,
                                               int* __restrict__ bsum) {
  int i4 = blockIdx.x * 256 + threadIdx.x;
  int4 d = {0, 0, 0, 0};
  if (i4 * 4 < N_NODES) d = ((const int4*)deg)[i4];
  int s = d.x + d.y + d.z + d.w;
#pragma unroll
  for (int off = 1; off < 64; off <<= 1) s += __shfl_xor(s, off, 64);
  __shared__ int ws[4];
  int lane = threadIdx.x & 63, w = threadIdx.x >> 6;
  if (lane == 0) ws[w] = s;
  __syncthreads();
  if (threadIdx.x == 0) bsum[blockIdx.x] = ws[0] + ws[1] + ws[2] + ws[3];
}

// Pass 2: exclusive scan of the 49 block sums (one wave).
__global__ void k_scan2(int* __restrict__ bsum) {
  int lane = threadIdx.x;
  int v = (lane < NSCAN_BLKS) ? bsum[lane] : 0;
  int x = v;
#pragma unroll
  for (int off = 1; off < 64; off <<= 1) {
    int t = __shfl_up(x, off, 64);
    if (lane >= off) x += t;
  }
  if (lane < NSCAN_BLKS) bsum[lane] = x - v;  // exclusive base
}

// Pass 3: per-block scan + base; writes offs[i+1..] and cursor[i..].
__global__ __launch_bounds__(256) void k_scan3(const int* __restrict__ deg,
                                               const int* __restrict__ bbase,
                                               int* __restrict__ offs,
                                               int* __restrict__ cursor) {
  int t = threadIdx.x, lane = t & 63, w = t >> 6;
  int i4 = blockIdx.x * 256 + t;
  int4 d = {0, 0, 0, 0};
  bool valid = (i4 * 4 < N_NODES);
  if (valid) d = ((const int4*)deg)[i4];
  int s0 = d.x, s1 = s0 + d.y, s2 = s1 + d.z, s3 = s2 + d.w;
  int x = s3;
#pragma unroll
  for (int off = 1; off < 64; off <<= 1) {
    int tt = __shfl_up(x, off, 64);
    if (lane >= off) x += tt;
  }
  __shared__ int ws[4];
  if (lane == 63) ws[w] = x;
  __syncthreads();
  int wadd = 0;
  for (int k = 0; k < w; ++k) wadd += ws[k];
  int base = bbase[blockIdx.x] + wadd + (x - s3);  // exclusive prefix of node i
  if (valid) {
    int i = i4 * 4;
    int4 cur = {base, base + s0, base + s1, base + s2};
    ((int4*)&cursor[i])[0] = cur;
    offs[i + 1] = base + s0;
    offs[i + 2] = base + s1;
    offs[i + 3] = base + s2;
    offs[i + 4] = base + s3;
  }
  if (blockIdx.x == 0 && t == 0) offs[0] = 0;
}

// Fused scatter: build srcs[] AND permute edge_attr into CSR order as fp16.
__global__ __launch_bounds__(256) void k_scatter(
    const int* __restrict__ src, const int* __restrict__ tgt,
    int* __restrict__ cursor, const float* __restrict__ ea,
    int* __restrict__ srcs, _Float16* __restrict__ eac) {
  int i = blockIdx.x * 32 + (threadIdx.x >> 3);
  int c = threadIdx.x & 7;
  int lane = threadIdx.x & 63;
  int pos = 0;
  if (c == 0) pos = atomicAdd(&cursor[tgt[i]], 1);
  pos = __shfl(pos, lane & 0x38, 64);   // broadcast from group leader
  if (c == 0) srcs[pos] = src[i];
  float4 v = *(const float4*)&ea[(size_t)i * HID + c * 4];
  half4v h = {(_Float16)v.x, (_Float16)v.y, (_Float16)v.z, (_Float16)v.w};
  *(half4v*)&eac[(size_t)pos * HID + c * 4] = h;
}

// ---------------- weight prep (fused transpose + p-fold) ----------------
__global__ __launch_bounds__(128) void k_prep_w(
    const float* __restrict__ wq, const float* __restrict__ wk,
    const float* __restrict__ wv, const float* __restrict__ ws,
    const float* __restrict__ bq, const float* __restrict__ we,
    _Float16* __restrict__ wt, float* __restrict__ bp) {
  int g = blockIdx.x;          // 0..639 output col
  int k = threadIdx.x;         // 0..127 input dim
  if (g < 512) {
    const float* w = (g < 128) ? wq : (g < 256) ? wk : (g < 384) ? wv : ws;
    int c = g & 127;
    wt[(size_t)g * HC + k] = (_Float16)w[k * HC + c];
  } else {
    int c = g - 512;
    int hb = (c >> 5) << 5, j = c & 31;
    float s = 0.f;
#pragma unroll
    for (int d = 0; d < 32; ++d)
      s = fmaf(wq[k * HC + hb + d], we[j * HC + hb + d], s);
    wt[(size_t)g * HC + k] = (_Float16)s;
    if (k == 0) {
      float b = 0.f;
      for (int d = 0; d < 32; ++d) b = fmaf(bq[hb + d], we[j * HC + hb + d], b);
      bp[c] = b;
    }
  }
}

// ---------------- MFMA node GEMM (merged-cb, LDS-staged B) ----------------
// Grid (782): 64 rows/block, 4 waves x 16 rows. A loaded ONCE to registers,
// then loop over the 5 output blocks (B staged per cb). A-traffic /5.
template <bool IN32>
__global__ __launch_bounds__(256) void k_gemm(
    const void* __restrict__ ain_,      // [N][128] fp32 (IN32) or fp16
    const _Float16* __restrict__ wt,    // [640][128] fp16 = W^T
    const float* __restrict__ bq, const float* __restrict__ bk,
    const float* __restrict__ bv, const float* __restrict__ bs,
    const float* __restrict__ bp,
    __half* __restrict__ qn16, _Float16* __restrict__ kv16,
    _Float16* __restrict__ sk16, __half* __restrict__ p16) {
  __shared__ _Float16 Bs[128][132];    // +4 halves pad: ds_read 2-way (free)
  int tid = threadIdx.x;
  int wv = tid >> 6, lane = tid & 63;
  int quad = lane >> 4, l16 = lane & 15;

  int r0 = blockIdx.x * 64 + wv * 16;
  int arow = min(r0 + l16, N_NODES - 1);
  half8 A[4];
#pragma unroll
  for (int kc = 0; kc < 4; ++kc) {
    if constexpr (IN32) {
      const float* ain = (const float*)ain_;
      const float4* ap = (const float4*)&ain[(size_t)arow * HC + kc * 32 + quad * 8];
      float4 a0 = ap[0], a1 = ap[1];
      A[kc] = (half8){(_Float16)a0.x, (_Float16)a0.y, (_Float16)a0.z,
                      (_Float16)a0.w, (_Float16)a1.x, (_Float16)a1.y,
                      (_Float16)a1.z, (_Float16)a1.w};
    } else {
      const _Float16* ain = (const _Float16*)ain_;
      A[kc] = *(const half8*)&ain[(size_t)arow * HC + kc * 32 + quad * 8];
    }
  }

#pragma unroll
  for (int cb = 0; cb < 5; ++cb) {
    __syncthreads();   // prior cb's ds_reads complete before overwrite
#pragma unroll
    for (int i = 0; i < 8; ++i) {
      int chunk = i * 256 + tid;
      int col = chunk >> 4, kc16 = chunk & 15;
      half8 b = *(const half8*)&wt[(size_t)(cb * 128 + col) * HC + kc16 * 8];
      *(half8*)&Bs[col][kc16 * 8] = b;
    }
    __syncthreads();

    floatx4 acc[8];
#pragma unroll
    for (int ct = 0; ct < 8; ++ct) acc[ct] = (floatx4){0.f, 0.f, 0.f, 0.f};
#pragma unroll
    for (int ct = 0; ct < 8; ++ct) {
#pragma unroll
      for (int kc = 0; kc < 4; ++kc) {
        half8 B = *(const half8*)&Bs[ct * 16 + l16][kc * 32 + quad * 8];
        acc[ct] = __builtin_amdgcn_mfma_f32_16x16x32_f16(A[kc], B, acc[ct], 0, 0, 0);
      }
    }

    const float* bias = (cb == 0) ? bq : (cb == 1) ? bk : (cb == 2) ? bv
                      : (cb == 3) ? bs : bp;
#pragma unroll
    for (int ct = 0; ct < 8; ++ct) {
      int lc = (ct << 4) + l16;
      float b = bias[lc];
#pragma unroll
      for (int reg = 0; reg < 4; ++reg) {
        int row = r0 + quad * 4 + reg;   // C/D: col=lane&15, row=quad*4+reg
        if (row < N_NODES) {
          float val = acc[ct][reg] + b;
          if (cb == 0) qn16[(size_t)row * HC + lc] = __float2half(val);
          else if (cb == 1) kv16[(size_t)row * 256 + lc] = (_Float16)val;
          else if (cb == 2) kv16[(size_t)row * 256 + 128 + lc] = (_Float16)val;
          else if (cb == 3) sk16[(size_t)row * HC + lc] = (_Float16)val;
          else p16[(size_t)row * HC + lc] = __float2half(val);
        }
      }
    }
  }
}

// ---------------- edge attention ----------------
// One wave per target. Per 16-edge chunk: batch-gather K/V/E to registers
// (12 independent loads = one latency exposure), compute from registers.
__device__ __forceinline__ float dot8(half8 a, half8 b, float c) {
#if __has_builtin(__builtin_amdgcn_fdot2)
#pragma unroll
  for (int i = 0; i < 4; ++i) {
    half2v x = {a[2 * i], a[2 * i + 1]};
    half2v y = {b[2 * i], b[2 * i + 1]};
    c = __builtin_amdgcn_fdot2(x, y, c, false);
  }
#else
#pragma unroll
  for (int i = 0; i < 8; ++i) c = fmaf((float)a[i], (float)b[i], c);
#endif
  return c;
}

// sum over the 4 lanes of a quad via DPP quad_perm (xor1 then xor2)
__device__ __forceinline__ float quad_red(float x) {
  int b = __builtin_amdgcn_update_dpp(0, __float_as_int(x), 0xB1, 0xF, 0xF, true);
  float y = x + __int_as_float(b);
  int c2 = __builtin_amdgcn_update_dpp(0, __float_as_int(y), 0x4E, 0xF, 0xF, true);
  return y + __int_as_float(c2);
}

__global__ __launch_bounds__(128) void k_edge_attn(
    const int* __restrict__ offs, const int* __restrict__ srcs,
    const _Float16* __restrict__ eac,
    const _Float16* __restrict__ qn, const _Float16* __restrict__ kv,
    const _Float16* __restrict__ sk,
    const _Float16* __restrict__ pn, const float* __restrict__ we,
    _Float16* __restrict__ o16) {
  int lane = threadIdx.x & 63;
  int wv_ = threadIdx.x >> 6;
  int t = blockIdx.x * TPB + wv_;
  int g = lane >> 4;          // edge subgroup 0..3
  int p = lane & 15;          // position within group
  int f0 = p << 3;            // feature base (8 feats, head = p>>2)
  int jd0 = (p & 3) << 3;     // ea-dim base (8 of 32 dims)

  half8 qh = *(const half8*)&qn[(size_t)t * HC + f0];
  half8 ph = *(const half8*)&pn[(size_t)t * HC + ((p >> 2) << 5) + jd0];

  int e0 = offs[t], e1 = offs[t + 1];
  const float inv_sqrt = 0.17677669529663687f;
  float den = 0.f;
  float acc[8], tac[8];
#pragma unroll
  for (int i = 0; i < 8; ++i) { acc[i] = 0.f; tac[i] = 0.f; }

  int sl = (e0 < e1) ? srcs[min(e0 + (lane & 15), e1 - 1)] : 0;
  for (int base = e0; base < e1; base += 16) {
    int cnt = e1 - base;               // remaining edges (>0)
    // ---- gather phase: 12 independent loads, all in flight at once ----
    half8 K[4], V[4], E[4];
#pragma unroll
    for (int i = 0; i < 4; ++i) {
      int j = 4 * g + i;
      int jc = min(j, cnt - 1);
      int s = __shfl(sl, jc, 64);
      const _Float16* kvp = &kv[(size_t)s * 256];
      K[i] = *(const half8*)&kvp[f0];
      V[i] = *(const half8*)&kvp[128 + f0];
      E[i] = *(const half8*)&eac[(size_t)(base + jc) * HID + jd0];
    }
    // issue next chunk's srcs load under the compute phase
    int nb = base + 16;
    int sl_n = (nb < e1) ? srcs[min(nb + (lane & 15), e1 - 1)] : 0;
    // ---- compute phase: 4 edges from registers ----
#pragma unroll
    for (int i = 0; i < 4; ++i) {
      int j = 4 * g + i;
      float part = dot8(qh, K[i], 0.f);
      part = dot8(ph, E[i], part);
      part = quad_red(part);           // full 32-dim dot for this head
      float w = (j < cnt) ? __expf(part * inv_sqrt) : 0.f;
      den += w;
#pragma unroll
      for (int q2 = 0; q2 < 8; ++q2) {
        acc[q2] = fmaf(w, (float)V[i][q2], acc[q2]);
        tac[q2] = fmaf(w, (float)E[i][q2], tac[q2]);
      }
    }
    sl = sl_n;
  }

  // merge the 4 edge-subgroups
#pragma unroll
  for (int i = 0; i < 8; ++i) {
    acc[i] += __shfl_xor(acc[i], 16, 64); acc[i] += __shfl_xor(acc[i], 32, 64);
    tac[i] += __shfl_xor(tac[i], 16, 64); tac[i] += __shfl_xor(tac[i], 32, 64);
  }
  den += __shfl_xor(den, 16, 64);
  den += __shfl_xor(den, 32, 64);

  // fx[f] = sum_j tac_h[j] * we[j][f]; j-range split across the 4 groups
  __shared__ float tl[TPB][16][9];
  if (g == 0) {
#pragma unroll
    for (int i = 0; i < 8; ++i) tl[wv_][p][i] = tac[i];
  }
  float fx[8];
#pragma unroll
  for (int i = 0; i < 8; ++i) fx[i] = 0.f;
  int r = (p & 12) + g;       // LDS row holding this head's j-range for group g
#pragma unroll
  for (int u = 0; u < 8; ++u) {
    float tv = tl[wv_][r][u];
    int j = (g << 3) + u;
    const float4* wr = (const float4*)&we[j * HC + f0];
    float4 w0 = wr[0], w1 = wr[1];
    fx[0] = fmaf(tv, w0.x, fx[0]); fx[1] = fmaf(tv, w0.y, fx[1]);
    fx[2] = fmaf(tv, w0.z, fx[2]); fx[3] = fmaf(tv, w0.w, fx[3]);
    fx[4] = fmaf(tv, w1.x, fx[4]); fx[5] = fmaf(tv, w1.y, fx[5]);
    fx[6] = fmaf(tv, w1.z, fx[6]); fx[7] = fmaf(tv, w1.w, fx[7]);
  }
#pragma unroll
  for (int i = 0; i < 8; ++i) {
    fx[i] += __shfl_xor(fx[i], 16, 64);
    fx[i] += __shfl_xor(fx[i], 32, 64);
  }

  if (g == 0) {
    float rd = (e1 > e0) ? (1.0f / den) : 0.f;
    half8 s8 = *(const half8*)&sk[(size_t)t * HC + f0];
    float o[8];
#pragma unroll
    for (int i = 0; i < 8; ++i) {
      o[i] = fmaf(acc[i] + fx[i], rd, (float)s8[i]);
      o[i] = o[i] > 0.f ? o[i] : __expf(o[i]) - 1.f;
    }
    half8 v16 = {(_Float16)o[0], (_Float16)o[1], (_Float16)o[2], (_Float16)o[3],
                 (_Float16)o[4], (_Float16)o[5], (_Float16)o[6], (_Float16)o[7]};
    *(half8*)&o16[(size_t)t * HC + f0] = v16;
  }
}

// ---------------- global mean pool (reads fp16 h) ----------------
__global__ __launch_bounds__(128) void k_pool_sum(const _Float16* __restrict__ h16,
                                                  const int* __restrict__ batch,
                                                  float* __restrict__ psum) {
  int c = threadIdx.x;
  int n0 = blockIdx.x * PNB;
  int n1 = n0 + PNB;
  float acc = 0.f;
  int curb = batch[n0];
  for (int n = n0; n < n1; ++n) {
    int b = batch[n];
    if (b != curb) {
      atomicAdd(&psum[curb * HC + c], acc);
      acc = 0.f;
      curb = b;
    }
    acc += (float)h16[(size_t)n * HC + c];
  }
  atomicAdd(&psum[curb * HC + c], acc);
}

// ---------------- classifier + log_softmax ----------------
__global__ __launch_bounds__(1024) void k_classify(const float* __restrict__ psum,
                                                   const int* __restrict__ batch,
                                                   const float* __restrict__ wlin,
                                                   const float* __restrict__ blin,
                                                   float* __restrict__ out) {
  int tid = threadIdx.x;
  int b = tid >> 4, o = tid & 15;
  int lo = 0, hi = N_NODES;
  while (lo < hi) { int mid = (lo + hi) >> 1; if (batch[mid] < b) lo = mid + 1; else hi = mid; }
  int start = lo;
  lo = 0; hi = N_NODES;
  while (lo < hi) { int mid = (lo + hi) >> 1; if (batch[mid] <= b) lo = mid + 1; else hi = mid; }
  float cnt = fmaxf((float)(lo - start), 1.0f);
  float dot = 0.f;
  for (int d = 0; d < HC; ++d) dot = fmaf(psum[b * HC + d], wlin[d * OUT_C + o], dot);
  float acc = dot / cnt + blin[o];
  float mx = acc;
#pragma unroll
  for (int off = 8; off > 0; off >>= 1) mx = fmaxf(mx, __shfl_xor(mx, off, 64));
  float ex = __expf(acc - mx);
  float sum = ex;
#pragma unroll
  for (int off = 8; off > 0; off >>= 1) sum += __shfl_xor(sum, off, 64);
  out[tid] = acc - mx - logf(sum);
}

extern "C" void kernel_launch(void* const* d_in, const int* in_sizes, int n_in,
                              void* d_out, int out_size, void* d_ws, size_t ws_size,
                              hipStream_t stream) {
  const float* x = (const float*)d_in[0];
  const int* ei = (const int*)d_in[1];
  const float* ea = (const float*)d_in[2];
  const int* batch = (const int*)d_in[3];
  const float* wq1 = (const float*)d_in[4];  const float* bq1 = (const float*)d_in[5];
  const float* wk1 = (const float*)d_in[6];  const float* bk1 = (const float*)d_in[7];
  const float* wv1 = (const float*)d_in[8];  const float* bv1 = (const float*)d_in[9];
  const float* we1 = (const float*)d_in[10];
  const float* ws1 = (const float*)d_in[11]; const float* bs1 = (const float*)d_in[12];
  const float* wq2 = (const float*)d_in[13]; const float* bq2 = (const float*)d_in[14];
  const float* wk2 = (const float*)d_in[15]; const float* bk2 = (const float*)d_in[16];
  const float* wv2 = (const float*)d_in[17]; const float* bv2 = (const float*)d_in[18];
  const float* we2 = (const float*)d_in[19];
  const float* ws2 = (const float*)d_in[20]; const float* bs2 = (const float*)d_in[21];
  const float* wlin = (const float*)d_in[22]; const float* blin = (const float*)d_in[23];

  const int* srcI = ei;
  const int* tgtI = ei + N_EDGES;

  char* wsb = (char*)d_ws;
  size_t off = 0;
  auto alloc = [&](size_t bytes) -> void* {
    void* ptr = wsb + off;
    off += (bytes + 255) & ~(size_t)255;
    return ptr;
  };
  __half* qn16 = (__half*)alloc((size_t)N_NODES * HC * 2);
  _Float16* kv16 = (_Float16*)alloc((size_t)N_NODES * 256 * 2);  // interleaved k|v
  __half* p16  = (__half*)alloc((size_t)N_NODES * HC * 2);
  _Float16* sk16 = (_Float16*)alloc((size_t)N_NODES * HC * 2);   // fp16 skip
  _Float16* h16 = (_Float16*)alloc((size_t)N_NODES * HC * 2);    // layer-2 output
  _Float16* in16 = (_Float16*)alloc((size_t)N_NODES * HC * 2);   // layer-1 output
  _Float16* wt1 = (_Float16*)alloc((size_t)640 * HC * 2);
  _Float16* wt2 = (_Float16*)alloc((size_t)640 * HC * 2);
  float* bp1 = (float*)alloc((size_t)HC * 4);
  float* bp2 = (float*)alloc((size_t)HC * 4);
  float* psum = (float*)alloc((size_t)NGRAPH * HC * 4);
  int* deg    = (int*)alloc((size_t)N_NODES * 4);
  int* offs   = (int*)alloc((size_t)(N_NODES + 1) * 4);
  int* cursor = (int*)alloc((size_t)N_NODES * 4);
  int* srcs   = (int*)alloc((size_t)N_EDGES * 4);
  int* bsum   = (int*)alloc((size_t)NSCAN_BLKS * 4);
  _Float16* eac = (_Float16*)alloc((size_t)N_EDGES * HID * 2);

  // CSR build (parallel 3-pass scan; scatter fused with edge_attr permute)
  hipMemsetAsync(deg, 0, (size_t)N_NODES * 4, stream);
  k_hist<<<(N_EDGES + 255) / 256, 256, 0, stream>>>(tgtI, deg);
  k_scan1<<<NSCAN_BLKS, 256, 0, stream>>>(deg, bsum);
  k_scan2<<<1, 64, 0, stream>>>(bsum);
  k_scan3<<<NSCAN_BLKS, 256, 0, stream>>>(deg, bsum, offs, cursor);
  k_scatter<<<N_EDGES / 32, 256, 0, stream>>>(srcI, tgtI, cursor, ea, srcs, eac);

  // Weight prep (fused transpose + p-fold), one dispatch per layer
  k_prep_w<<<640, 128, 0, stream>>>(wq1, wk1, wv1, ws1, bq1, we1, wt1, bp1);
  k_prep_w<<<640, 128, 0, stream>>>(wq2, wk2, wv2, ws2, bq2, we2, wt2, bp2);

  int gemm_grid = (N_NODES + 63) / 64;   // 782; cb loop merged in-kernel
  // Layer 1 (reads fp32 x directly; in-register fp16 convert == old conv_x)
  k_gemm<true><<<gemm_grid, 256, 0, stream>>>(x, wt1, bq1, bk1, bv1, bs1, bp1,
                                              qn16, kv16, sk16, p16);
  k_edge_attn<<<N_NODES / TPB, 64 * TPB, 0, stream>>>(
      offs, srcs, eac, (const _Float16*)qn16, kv16, sk16,
      (const _Float16*)p16, we1, in16);
  // Layer 2
  k_gemm<false><<<gemm_grid, 256, 0, stream>>>(in16, wt2, bq2, bk2, bv2, bs2, bp2,
                                               qn16, kv16, sk16, p16);
  k_edge_attn<<<N_NODES / TPB, 64 * TPB, 0, stream>>>(
      offs, srcs, eac, (const _Float16*)qn16, kv16, sk16,
      (const _Float16*)p16, we2, h16);

  // Pool + classify
  hipMemsetAsync(psum, 0, (size_t)NGRAPH * HC * 4, stream);
  k_pool_sum<<<N_NODES / PNB, 128, 0, stream>>>(h16, batch, psum);
  k_classify<<<1, 1024, 0, stream>>>(psum, batch, wlin, blin, (float*)d_out);
}